// Round 8
// baseline (1337.515 us; speedup 1.0000x reference)
//
#include <hip/hip_runtime.h>
#include <cstdint>
#include <cstddef>

#define NN 50000
#define NE 400000
#define NG 256
#define DIM 200
#define NSTEPS 6

typedef unsigned int uint;
typedef unsigned short ushort;
typedef __attribute__((ext_vector_type(8))) short short8;
typedef __attribute__((ext_vector_type(4))) float f32x4;

#define GLL16(gsrc, ldst)                                                        \
  __builtin_amdgcn_global_load_lds(                                              \
      (const __attribute__((address_space(1))) void*)(gsrc),                     \
      (__attribute__((address_space(3))) void*)(ldst), 16, 0, 0)

// ---- packed split-bf16 helpers: word = (hi_bf16 << 16) | lo_bf16 ----
__device__ __forceinline__ float up_hi(uint w) { return __uint_as_float(w & 0xffff0000u); }
__device__ __forceinline__ float up_lo(uint w) { return __uint_as_float(w << 16); }
__device__ __forceinline__ float up_f(uint w) { return up_hi(w) + up_lo(w); }
__device__ __forceinline__ uint packf(float v) {
  uint u = __float_as_uint(v);
  uint t = u + 0x7fffu + ((u >> 16) & 1u);   // RN-even to bf16
  uint hb = t & 0xffff0000u;
  float lo = v - __uint_as_float(hb);
  uint ul = __float_as_uint(lo);
  uint t2 = ul + 0x7fffu + ((ul >> 16) & 1u);
  return hb | (t2 >> 16);
}
__device__ __forceinline__ ushort bf16rn(float v) {
  uint u = __float_as_uint(v);
  return (ushort)((u + 0x7fffu + ((u >> 16) & 1u)) >> 16);
}

// ---------------- utility kernels ----------------
__global__ void k_zero_i32(int* __restrict__ p, int n) {
  for (int i = blockIdx.x * blockDim.x + threadIdx.x; i < n; i += gridDim.x * blockDim.x)
    p[i] = 0;
}
__global__ void k_zero_f32(float* __restrict__ p, int n) {
  for (int i = blockIdx.x * blockDim.x + threadIdx.x; i < n; i += gridDim.x * blockDim.x)
    p[i] = 0.f;
}
__global__ void k_copy_i32(const int* __restrict__ a, int* __restrict__ b, int n) {
  for (int i = blockIdx.x * blockDim.x + threadIdx.x; i < n; i += gridDim.x * blockDim.x)
    b[i] = a[i];
}
__global__ void k_hist(const int* __restrict__ dst, int* __restrict__ cnt, int nE) {
  int e = blockIdx.x * blockDim.x + threadIdx.x;
  if (e < nE) atomicAdd(&cnt[dst[e]], 1);
}
__global__ void k_scan(const int* __restrict__ cnt, int* __restrict__ off, int n) {
  __shared__ int buf[1024];
  __shared__ int carry;
  int tid = threadIdx.x;
  if (tid == 0) { carry = 0; off[0] = 0; }
  __syncthreads();
  for (int base = 0; base < n; base += 1024) {
    int i = base + tid;
    int v = (i < n) ? cnt[i] : 0;
    buf[tid] = v;
    __syncthreads();
    for (int d = 1; d < 1024; d <<= 1) {
      int t = (tid >= d) ? buf[tid - d] : 0;
      __syncthreads();
      buf[tid] += t;
      __syncthreads();
    }
    if (i < n) off[i + 1] = carry + buf[tid];
    __syncthreads();
    if (tid == 0) carry += buf[1023];
    __syncthreads();
  }
}
__global__ void k_scatter(const int* __restrict__ dst, const int* __restrict__ src,
                          int* __restrict__ cursor, int* __restrict__ slist, int nE) {
  int e = blockIdx.x * blockDim.x + threadIdx.x;
  if (e < nE) {
    int d = dst[e];
    int pos = atomicAdd(&cursor[d], 1);
    slist[pos] = src[e];
  }
}

// pack fp32 array -> packed split-bf16 (vectorized)
__global__ void k_pack_f32(const float4* __restrict__ in, uint4* __restrict__ out, int n4) {
  for (int i = blockIdx.x * blockDim.x + threadIdx.x; i < n4; i += gridDim.x * blockDim.x) {
    float4 v = in[i];
    uint4 o;
    o.x = packf(v.x); o.y = packf(v.y); o.z = packf(v.z); o.w = packf(v.w);
    out[i] = o;
  }
}

// elementwise fp32 -> bf16 ushort
__global__ void k_pack_bf(const float* __restrict__ in, ushort* __restrict__ out, int n) {
  for (int i = blockIdx.x * blockDim.x + threadIdx.x; i < n; i += gridDim.x * blockDim.x)
    out[i] = bf16rn(in[i]);
}

// transpose+pack: Wc fp32 [200][600] -> bf16 ushort [600][200]
__global__ void k_pack_wcT(const float* __restrict__ Wc, ushort* __restrict__ out) {
  int idx = blockIdx.x * blockDim.x + threadIdx.x;
  if (idx < 600 * DIM) {
    int c = idx / DIM, k = idx - c * DIM;
    out[idx] = bf16rn(Wc[(size_t)k * 600 + c]);
  }
}

// ---------------- fp32 GEMM (tiny, for Wc = W @ w_ih^T) ----------------
#define GBM 64
#define GBN 64
#define GBK 8
__global__ __launch_bounds__(256) void k_gemm_bt(const float* __restrict__ A,
                                                 const float* __restrict__ B,
                                                 float* __restrict__ C,
                                                 int M, int N, int K) {
  __shared__ __align__(16) float As[GBK][GBM];
  __shared__ __align__(16) float Bs[GBK][GBN];
  int tid = threadIdx.x;
  int row0 = blockIdx.y * GBM;
  int col0 = blockIdx.x * GBN;
  int ty = tid >> 4, tx = tid & 15;
  float acc[4][4] = {};
  for (int k0 = 0; k0 < K; k0 += GBK) {
    {
      int r = tid >> 2;
      int kk = (tid & 3) * 2;
      int gr = row0 + r;
      float2 v = make_float2(0.f, 0.f);
      if (gr < M) v = *reinterpret_cast<const float2*>(&A[(size_t)gr * K + k0 + kk]);
      As[kk][r] = v.x; As[kk + 1][r] = v.y;
    }
    {
      int n = tid >> 2;
      int kk = (tid & 3) * 2;
      int gn = col0 + n;
      float2 v = make_float2(0.f, 0.f);
      if (gn < N) v = *reinterpret_cast<const float2*>(&B[(size_t)gn * K + k0 + kk]);
      Bs[kk][n] = v.x; Bs[kk + 1][n] = v.y;
    }
    __syncthreads();
#pragma unroll
    for (int k = 0; k < GBK; ++k) {
      float4 av = *reinterpret_cast<const float4*>(&As[k][ty * 4]);
      float4 bv = *reinterpret_cast<const float4*>(&Bs[k][tx * 4]);
      float a[4] = {av.x, av.y, av.z, av.w};
      float b[4] = {bv.x, bv.y, bv.z, bv.w};
#pragma unroll
      for (int i = 0; i < 4; ++i)
#pragma unroll
        for (int j = 0; j < 4; ++j) acc[i][j] += a[i] * b[j];
    }
    __syncthreads();
  }
#pragma unroll
  for (int i = 0; i < 4; ++i) {
    int r = row0 + ty * 4 + i;
    if (r >= M) continue;
#pragma unroll
    for (int j = 0; j < 4; ++j) {
      int c = col0 + tx * 4 + j;
      if (c < N) C[(size_t)r * N + c] = acc[i][j];
    }
  }
}

// ---------------- aggregation: wave per node, 4-deep gather MLP ----------------
__global__ __launch_bounds__(256) void k_aggregate_pk(const uint* __restrict__ hpk,
                                                      const int* __restrict__ off,
                                                      const int* __restrict__ slist,
                                                      uint* __restrict__ aggpk) {
  int node = blockIdx.x * 4 + (threadIdx.x >> 6);
  if (node >= NN) return;
  int lane = threadIdx.x & 63;
  int c4 = lane * 4;
  bool act = c4 < DIM;
  float a0 = 0.f, a1 = 0.f, a2 = 0.f, a3 = 0.f;
  int beg = off[node], end = off[node + 1];
  int p = beg;
  for (; p + 3 < end; p += 4) {
    int s0 = slist[p], s1 = slist[p + 1], s2 = slist[p + 2], s3 = slist[p + 3];
    if (act) {
      uint4 u0 = *reinterpret_cast<const uint4*>(hpk + (size_t)s0 * DIM + c4);
      uint4 u1 = *reinterpret_cast<const uint4*>(hpk + (size_t)s1 * DIM + c4);
      uint4 u2 = *reinterpret_cast<const uint4*>(hpk + (size_t)s2 * DIM + c4);
      uint4 u3 = *reinterpret_cast<const uint4*>(hpk + (size_t)s3 * DIM + c4);
      a0 += (up_f(u0.x) + up_f(u1.x)) + (up_f(u2.x) + up_f(u3.x));
      a1 += (up_f(u0.y) + up_f(u1.y)) + (up_f(u2.y) + up_f(u3.y));
      a2 += (up_f(u0.z) + up_f(u1.z)) + (up_f(u2.z) + up_f(u3.z));
      a3 += (up_f(u0.w) + up_f(u1.w)) + (up_f(u2.w) + up_f(u3.w));
    }
  }
  for (; p < end; ++p) {
    int s = slist[p];
    if (act) {
      uint4 u = *reinterpret_cast<const uint4*>(hpk + (size_t)s * DIM + c4);
      a0 += up_f(u.x); a1 += up_f(u.y); a2 += up_f(u.z); a3 += up_f(u.w);
    }
  }
  if (act) {
    uint4 o;
    o.x = packf(a0); o.y = packf(a1); o.z = packf(a2); o.w = packf(a3);
    *reinterpret_cast<uint4*>(aggpk + (size_t)node * DIM + c4) = o;
  }
}

// ---------------- fused MFMA GRU step (barrier-free persistent, 16-col) -------
// Block: 256 thr (4 waves). B slice (6 mats x 25 chunks x 16 cols) resident in
// LDS (38KB -> 4 blocks/CU). A per-lane global->reg dbuf, split-bf16 exact.
// Block loops over 11 row-panels of 64 rows; ONE barrier total.
#define NPAN 782            // ceil(NN/64)
#define PPC 11              // panels per chunk
#define NCHK 72             // 72*11 = 792 >= 782
#define NCOLB 13            // 13*16 = 208 >= 200
#define GRIDF (NCOLB * NCHK)  // 936 = 8*117

// v_perm unpack: hi word-pair / lo word-pair selects
__device__ __forceinline__ void unpack16(const uint4 p0, const uint4 p1,
                                         short8& hi, short8& lo) {
  union U { uint u[4]; short8 s; };
  U H, L;
  H.u[0] = __builtin_amdgcn_perm(p0.y, p0.x, 0x07060302u);
  H.u[1] = __builtin_amdgcn_perm(p0.w, p0.z, 0x07060302u);
  H.u[2] = __builtin_amdgcn_perm(p1.y, p1.x, 0x07060302u);
  H.u[3] = __builtin_amdgcn_perm(p1.w, p1.z, 0x07060302u);
  L.u[0] = __builtin_amdgcn_perm(p0.y, p0.x, 0x05040100u);
  L.u[1] = __builtin_amdgcn_perm(p0.w, p0.z, 0x05040100u);
  L.u[2] = __builtin_amdgcn_perm(p1.y, p1.x, 0x05040100u);
  L.u[3] = __builtin_amdgcn_perm(p1.w, p1.z, 0x05040100u);
  hi = H.s; lo = L.s;
}

#define MFMA16(a, b, c) __builtin_amdgcn_mfma_f32_16x16x32_bf16(a, b, c, 0, 0, 0)

__global__ __launch_bounds__(256, 4) void k_fused_mfma(
    const uint* __restrict__ aggpk, const uint* __restrict__ hpk,
    const ushort* __restrict__ wcB, const ushort* __restrict__ whB,
    const float* __restrict__ b_ih, const float* __restrict__ b_hh,
    uint* __restrict__ hnextpk) {
  __shared__ uint4 BbRaw[2432];   // 6*25*16 = 2400 + 32 pad (38 KB)
#define BB(m, ch, c) BbRaw[(m) * 400 + (ch) * 16 + (c)]

  int tid = threadIdx.x;
  int lane = tid & 63;
  int wv = tid >> 6;          // 0..3
  int lr = lane & 15;
  int kc = lane >> 4;         // 0..3

  // XCD-aware swizzle: nwg = 936 = 8*117 exactly
  int x = blockIdx.x & 7, ii = blockIdx.x >> 3;
  int work = x * 117 + ii;
  int chunk = work / NCOLB;
  int col = work - chunk * NCOLB;
  int cc0 = col * 16;

  // ---- stage B once; every gll iteration uses full waves (2432 = 38 waves) ----
  {
    uint4* BbF = &BbRaw[0];
    for (int i2 = 0; i2 < 10; ++i2) {
      int u = tid + i2 * 256;
      if (u < 2432) {
        int us = u < 2400 ? u : 2399;     // pad units: duplicate source, dest in pad
        int mat = us / 400;
        int rem = us - mat * 400;
        int ch = rem >> 4;
        int c = rem & 15;
        int gc = cc0 + c; if (gc > 199) gc = 199;
        const ushort* wsrc = (mat & 1) ? whB : wcB;
        const ushort* sp = wsrc + (size_t)((mat >> 1) * DIM + gc) * DIM + ch * 8;
        GLL16(sp, BbF + u);
      }
    }
  }
  __syncthreads();   // the ONLY block-wide barrier

  for (int j = 0; j < PPC; ++j) {
    int p = chunk * PPC + j;
    if (p >= NPAN) break;
    int prow0 = p * 64;
    int rw = prow0 + wv * 16 + lr;           // this lane's A-fragment row
    int rcl = rw < NN ? rw : NN - 1;
    const uint* arow = aggpk + (size_t)rcl * DIM;
    const uint* hrow = hpk + (size_t)rcl * DIM;
    int k0 = kc * 8;

    f32x4 ai[3] = {};
    f32x4 ah[3] = {};
    uint4 aq[2][2], hq[2][2];
    aq[0][0] = *reinterpret_cast<const uint4*>(arow + k0);
    aq[0][1] = *reinterpret_cast<const uint4*>(arow + k0 + 4);
    hq[0][0] = *reinterpret_cast<const uint4*>(hrow + k0);
    hq[0][1] = *reinterpret_cast<const uint4*>(hrow + k0 + 4);

#pragma unroll
    for (int t = 0; t < 7; ++t) {
      const int cur = t & 1, nxt = cur ^ 1;
      if (t < 6) {
        if (t == 5) {   // tile 6 tail: only kc==0 (k 192-199) valid
          bool vld = (kc == 0);
          uint4 z = make_uint4(0, 0, 0, 0);
          aq[nxt][0] = vld ? *reinterpret_cast<const uint4*>(arow + 192) : z;
          aq[nxt][1] = vld ? *reinterpret_cast<const uint4*>(arow + 196) : z;
          hq[nxt][0] = vld ? *reinterpret_cast<const uint4*>(hrow + 192) : z;
          hq[nxt][1] = vld ? *reinterpret_cast<const uint4*>(hrow + 196) : z;
        } else {
          int ko = (t + 1) * 32 + k0;
          aq[nxt][0] = *reinterpret_cast<const uint4*>(arow + ko);
          aq[nxt][1] = *reinterpret_cast<const uint4*>(arow + ko + 4);
          hq[nxt][0] = *reinterpret_cast<const uint4*>(hrow + ko);
          hq[nxt][1] = *reinterpret_cast<const uint4*>(hrow + ko + 4);
        }
      }
      short8 aghi, aglo, hhi, hlo;
      unpack16(aq[cur][0], aq[cur][1], aghi, aglo);
      unpack16(hq[cur][0], hq[cur][1], hhi, hlo);
      int bch = t * 4 + kc; if (bch > 24) bch = 24;   // clamped rows have A=0
#pragma unroll
      for (int g = 0; g < 3; ++g) {
        short8 b1 = *reinterpret_cast<const short8*>(&BB(g * 2 + 0, bch, lr));
        short8 b2 = *reinterpret_cast<const short8*>(&BB(g * 2 + 1, bch, lr));
        ai[g] = MFMA16(aghi, b1, ai[g]);
        ai[g] = MFMA16(aglo, b1, ai[g]);
        ah[g] = MFMA16(hhi, b2, ah[g]);
        ah[g] = MFMA16(hlo, b2, ah[g]);
      }
    }

    // ---- epilogue: GRU gates for this panel's 16x16 wave-tile ----
    int c = cc0 + lr;
    if (c < DIM) {
      uint hvw[4];
#pragma unroll
      for (int qq = 0; qq < 4; ++qq) {
        int r_ = prow0 + wv * 16 + kc * 4 + qq;
        int rc = r_ < NN ? r_ : NN - 1;
        hvw[qq] = hpk[(size_t)rc * DIM + c];
      }
      float bir = b_ih[c], biz = b_ih[DIM + c], bin = b_ih[2 * DIM + c];
      float bhr = b_hh[c], bhz = b_hh[DIM + c], bhn = b_hh[2 * DIM + c];
#pragma unroll
      for (int qq = 0; qq < 4; ++qq) {
        int r_ = prow0 + wv * 16 + kc * 4 + qq;
        if (r_ >= NN) continue;
        float gir = ai[0][qq] + bir;
        float giz = ai[1][qq] + biz;
        float gin = ai[2][qq] + bin;
        float ghr = ah[0][qq] + bhr;
        float ghz = ah[1][qq] + bhz;
        float ghn = ah[2][qq] + bhn;
        float rr = 1.f / (1.f + __expf(-(gir + ghr)));
        float zz = 1.f / (1.f + __expf(-(giz + ghz)));
        float nn = tanhf(gin + rr * ghn);
        float hv = up_f(hvw[qq]);
        hnextpk[(size_t)r_ * DIM + c] = packf((1.f - zz) * nn + zz * hv);
      }
    }
  }
}

// ---------------- relu + segment_max pooling (packed h) ----------------
__global__ __launch_bounds__(256) void k_pool(const uint* __restrict__ hpk,
                                              const int* __restrict__ batch,
                                              float* __restrict__ pooled) {
  int i = blockIdx.x;
  int j = threadIdx.x;
  if (j < DIM) {
    int g = batch[i];
    float v = up_f(hpk[(size_t)i * DIM + j]);
    v = v > 0.f ? v : 0.f;
    atomicMax((int*)&pooled[(size_t)g * DIM + j], __float_as_int(v));
  }
}

__global__ __launch_bounds__(256) void k_classify(const float* __restrict__ pooled,
                                                  const float* __restrict__ w,
                                                  const float* __restrict__ b,
                                                  float* __restrict__ out) {
  __shared__ float r0[256], r1[256];
  int g = blockIdx.x;
  int j = threadIdx.x;
  float p = (j < DIM) ? pooled[(size_t)g * DIM + j] : 0.f;
  r0[j] = (j < DIM) ? p * w[j] : 0.f;
  r1[j] = (j < DIM) ? p * w[DIM + j] : 0.f;
  __syncthreads();
  for (int d = 128; d > 0; d >>= 1) {
    if (j < d) { r0[j] += r0[j + d]; r1[j] += r1[j + d]; }
    __syncthreads();
  }
  if (j == 0) {
    out[g * 2 + 0] = 1.f / (1.f + expf(-(r0[0] + b[0])));
    out[g * 2 + 1] = 1.f / (1.f + expf(-(r1[0] + b[1])));
  }
}

// ---------------- host ----------------
extern "C" void kernel_launch(void* const* d_in, const int* in_sizes, int n_in,
                              void* d_out, int out_size, void* d_ws, size_t ws_size,
                              hipStream_t stream) {
  const float* x = (const float*)d_in[0];
  const int* edge_index = (const int*)d_in[1];
  const int* batch = (const int*)d_in[2];
  const float* ggnn_w = (const float*)d_in[3];
  const float* w_ih = (const float*)d_in[4];
  const float* w_hh = (const float*)d_in[5];
  const float* b_ih = (const float*)d_in[6];
  const float* b_hh = (const float*)d_in[7];
  const float* cls_w = (const float*)d_in[8];
  const float* cls_b = (const float*)d_in[9];
  float* out = (float*)d_out;

  const int* src = edge_index;       // edge_index[0]
  const int* dst = edge_index + NE;  // edge_index[1]

  char* wsb = (char*)d_ws;
  size_t off = 0;
  auto alloc = [&](size_t bytes) -> void* {
    void* p = wsb + off;
    off += (bytes + 255) & ~(size_t)255;
    return p;
  };
  uint* hpkA = (uint*)alloc((size_t)NN * DIM * 4);   // 40 MB
  uint* hpkB = (uint*)alloc((size_t)NN * DIM * 4);   // 40 MB
  uint* aggpk = (uint*)alloc((size_t)NN * DIM * 4);  // 40 MB
  float* Wc_tmp = (float*)alloc((size_t)DIM * 3 * DIM * 4);
  ushort* wcB = (ushort*)alloc((size_t)NSTEPS * 3 * DIM * DIM * 2);  // 1.44 MB
  ushort* whB = (ushort*)alloc((size_t)3 * DIM * DIM * 2);           // 240 KB
  float* pooled = (float*)alloc((size_t)NG * DIM * 4);
  int* indeg = (int*)alloc((size_t)NN * 4);
  int* offs = (int*)alloc((size_t)(NN + 1) * 4);
  int* slist = (int*)alloc((size_t)NE * 4);
  if (off > ws_size) return;  // fail loud (absmax) instead of faulting

  // h0 = pack(x)
  k_pack_f32<<<2048, 256, 0, stream>>>((const float4*)x, (uint4*)hpkA, NN * DIM / 4);

  // CSR build (dst -> src list)
  k_zero_i32<<<196, 256, 0, stream>>>(indeg, NN);
  k_hist<<<(NE + 255) / 256, 256, 0, stream>>>(dst, indeg, NE);
  k_scan<<<1, 1024, 0, stream>>>(indeg, offs, NN);
  k_copy_i32<<<196, 256, 0, stream>>>(offs, indeg, NN);
  k_scatter<<<(NE + 255) / 256, 256, 0, stream>>>(dst, src, indeg, slist, NE);

  // weights: Wc[s] = ggnn_w[s] @ w_ih^T -> bf16 [600][200]; whB = bf16(w_hh)
  {
    dim3 g((3 * DIM + GBN - 1) / GBN, (DIM + GBM - 1) / GBM);
    for (int s = 0; s < NSTEPS; ++s) {
      k_gemm_bt<<<g, 256, 0, stream>>>(ggnn_w + (size_t)s * DIM * DIM, w_ih, Wc_tmp,
                                       DIM, 3 * DIM, DIM);
      k_pack_wcT<<<(600 * DIM + 255) / 256, 256, 0, stream>>>(
          Wc_tmp, wcB + (size_t)s * 3 * DIM * DIM);
    }
    k_pack_bf<<<512, 256, 0, stream>>>(w_hh, whB, 3 * DIM * DIM);
  }

  uint* hcur = hpkA;
  uint* hnext = hpkB;
  for (int s = 0; s < NSTEPS; ++s) {
    k_aggregate_pk<<<(NN + 3) / 4, 256, 0, stream>>>(hcur, offs, slist, aggpk);
    k_fused_mfma<<<GRIDF, 256, 0, stream>>>(aggpk, hcur,
                                            wcB + (size_t)s * 3 * DIM * DIM,
                                            whB, b_ih, b_hh, hnext);
    uint* t = hcur; hcur = hnext; hnext = t;
  }

  k_zero_f32<<<200, 256, 0, stream>>>(pooled, NG * DIM);
  k_pool<<<NN, 256, 0, stream>>>(hcur, batch, pooled);
  k_classify<<<NG, 256, 0, stream>>>(pooled, cls_w, cls_b, out);
}

// Round 9
// 1312.233 us; speedup vs baseline: 1.0193x; 1.0193x over previous
//
#include <hip/hip_runtime.h>
#include <cstdint>
#include <cstddef>

#define NN 50000
#define NE 400000
#define NG 256
#define DIM 200
#define NSTEPS 6
#define ROWW 400   // ushorts per row: 25 chunks x (8 hi | 8 lo)

typedef unsigned int uint;
typedef unsigned short ushort;
typedef __attribute__((ext_vector_type(8))) short short8;
typedef __attribute__((ext_vector_type(4))) float f32x4;

#define GLL16(gsrc, ldst)                                                        \
  __builtin_amdgcn_global_load_lds(                                              \
      (const __attribute__((address_space(1))) void*)(gsrc),                     \
      (__attribute__((address_space(3))) void*)(ldst), 16, 0, 0)

__device__ __forceinline__ float bfu(ushort u) { return __uint_as_float((uint)u << 16); }
__device__ __forceinline__ uint packf(float v) {   // (hi_bf16<<16)|lo_bf16, RN-even
  uint u = __float_as_uint(v);
  uint t = u + 0x7fffu + ((u >> 16) & 1u);
  uint hb = t & 0xffff0000u;
  float lo = v - __uint_as_float(hb);
  uint ul = __float_as_uint(lo);
  uint t2 = ul + 0x7fffu + ((ul >> 16) & 1u);
  return hb | (t2 >> 16);
}
__device__ __forceinline__ ushort bf16rn(float v) {
  uint u = __float_as_uint(v);
  return (ushort)((u + 0x7fffu + ((u >> 16) & 1u)) >> 16);
}
__device__ __forceinline__ short8 s8(uint4 v) {
  union { uint4 u; short8 s; } c; c.u = v; return c.s;
}

// ---------------- utility kernels ----------------
__global__ void k_zero_i32(int* __restrict__ p, int n) {
  for (int i = blockIdx.x * blockDim.x + threadIdx.x; i < n; i += gridDim.x * blockDim.x)
    p[i] = 0;
}
__global__ void k_zero_f32(float* __restrict__ p, int n) {
  for (int i = blockIdx.x * blockDim.x + threadIdx.x; i < n; i += gridDim.x * blockDim.x)
    p[i] = 0.f;
}
__global__ void k_copy_i32(const int* __restrict__ a, int* __restrict__ b, int n) {
  for (int i = blockIdx.x * blockDim.x + threadIdx.x; i < n; i += gridDim.x * blockDim.x)
    b[i] = a[i];
}
__global__ void k_hist(const int* __restrict__ dst, int* __restrict__ cnt, int nE) {
  int e = blockIdx.x * blockDim.x + threadIdx.x;
  if (e < nE) atomicAdd(&cnt[dst[e]], 1);
}
__global__ void k_scan(const int* __restrict__ cnt, int* __restrict__ off, int n) {
  __shared__ int buf[1024];
  __shared__ int carry;
  int tid = threadIdx.x;
  if (tid == 0) { carry = 0; off[0] = 0; }
  __syncthreads();
  for (int base = 0; base < n; base += 1024) {
    int i = base + tid;
    int v = (i < n) ? cnt[i] : 0;
    buf[tid] = v;
    __syncthreads();
    for (int d = 1; d < 1024; d <<= 1) {
      int t = (tid >= d) ? buf[tid - d] : 0;
      __syncthreads();
      buf[tid] += t;
      __syncthreads();
    }
    if (i < n) off[i + 1] = carry + buf[tid];
    __syncthreads();
    if (tid == 0) carry += buf[1023];
    __syncthreads();
  }
}
__global__ void k_scatter(const int* __restrict__ dst, const int* __restrict__ src,
                          int* __restrict__ cursor, int* __restrict__ slist, int nE) {
  int e = blockIdx.x * blockDim.x + threadIdx.x;
  if (e < nE) {
    int d = dst[e];
    int pos = atomicAdd(&cursor[d], 1);
    slist[pos] = src[e];
  }
}

// fp32 [NN][200] -> plane format hP [NN][25][(8 hi)(8 lo)]
__global__ void k_pack_planes(const float* __restrict__ x, ushort* __restrict__ hP,
                              int nch) {
  for (int i = blockIdx.x * blockDim.x + threadIdx.x; i < nch;
       i += gridDim.x * blockDim.x) {
    int row = i / 25, ch = i - row * 25;
    const float* s = x + (size_t)row * 200 + ch * 8;
    uint w[8];
#pragma unroll
    for (int j = 0; j < 8; ++j) w[j] = packf(s[j]);
    uint4 hi, lo;
    hi.x = (w[0] >> 16) | (w[1] & 0xffff0000u);
    hi.y = (w[2] >> 16) | (w[3] & 0xffff0000u);
    hi.z = (w[4] >> 16) | (w[5] & 0xffff0000u);
    hi.w = (w[6] >> 16) | (w[7] & 0xffff0000u);
    lo.x = (w[0] & 0xffffu) | (w[1] << 16);
    lo.y = (w[2] & 0xffffu) | (w[3] << 16);
    lo.z = (w[4] & 0xffffu) | (w[5] << 16);
    lo.w = (w[6] & 0xffffu) | (w[7] << 16);
    ushort* d = hP + (size_t)row * ROWW + ch * 16;
    *reinterpret_cast<uint4*>(d) = hi;
    *reinterpret_cast<uint4*>(d + 8) = lo;
  }
}

// elementwise fp32 -> bf16 ushort
__global__ void k_pack_bf(const float* __restrict__ in, ushort* __restrict__ out, int n) {
  for (int i = blockIdx.x * blockDim.x + threadIdx.x; i < n; i += gridDim.x * blockDim.x)
    out[i] = bf16rn(in[i]);
}

// transpose+pack: Wc fp32 [200][600] -> bf16 ushort [600][200]
__global__ void k_pack_wcT(const float* __restrict__ Wc, ushort* __restrict__ out) {
  int idx = blockIdx.x * blockDim.x + threadIdx.x;
  if (idx < 600 * DIM) {
    int c = idx / DIM, k = idx - c * DIM;
    out[idx] = bf16rn(Wc[(size_t)k * 600 + c]);
  }
}

// ---------------- fp32 GEMM (tiny, for Wc = W @ w_ih^T) ----------------
#define GBM 64
#define GBN 64
#define GBK 8
__global__ __launch_bounds__(256) void k_gemm_bt(const float* __restrict__ A,
                                                 const float* __restrict__ B,
                                                 float* __restrict__ C,
                                                 int M, int N, int K) {
  __shared__ __align__(16) float As[GBK][GBM];
  __shared__ __align__(16) float Bs[GBK][GBN];
  int tid = threadIdx.x;
  int row0 = blockIdx.y * GBM;
  int col0 = blockIdx.x * GBN;
  int ty = tid >> 4, tx = tid & 15;
  float acc[4][4] = {};
  for (int k0 = 0; k0 < K; k0 += GBK) {
    {
      int r = tid >> 2;
      int kk = (tid & 3) * 2;
      int gr = row0 + r;
      float2 v = make_float2(0.f, 0.f);
      if (gr < M) v = *reinterpret_cast<const float2*>(&A[(size_t)gr * K + k0 + kk]);
      As[kk][r] = v.x; As[kk + 1][r] = v.y;
    }
    {
      int n = tid >> 2;
      int kk = (tid & 3) * 2;
      int gn = col0 + n;
      float2 v = make_float2(0.f, 0.f);
      if (gn < N) v = *reinterpret_cast<const float2*>(&B[(size_t)gn * K + k0 + kk]);
      Bs[kk][n] = v.x; Bs[kk + 1][n] = v.y;
    }
    __syncthreads();
#pragma unroll
    for (int k = 0; k < GBK; ++k) {
      float4 av = *reinterpret_cast<const float4*>(&As[k][ty * 4]);
      float4 bv = *reinterpret_cast<const float4*>(&Bs[k][tx * 4]);
      float a[4] = {av.x, av.y, av.z, av.w};
      float b[4] = {bv.x, bv.y, bv.z, bv.w};
#pragma unroll
      for (int i = 0; i < 4; ++i)
#pragma unroll
        for (int j = 0; j < 4; ++j) acc[i][j] += a[i] * b[j];
    }
    __syncthreads();
  }
#pragma unroll
  for (int i = 0; i < 4; ++i) {
    int r = row0 + ty * 4 + i;
    if (r >= M) continue;
#pragma unroll
    for (int j = 0; j < 4; ++j) {
      int c = col0 + tx * 4 + j;
      if (c < N) C[(size_t)r * N + c] = acc[i][j];
    }
  }
}

// ---------------- aggregation (plane format): wave per node ----------------
// Row = 50 uint4; lane u<50 owns uint4 u (chunk u>>1, half u&1). Sums its 8
// bf16 values; pair-combine via shfl_xor(1); each half re-packs its plane.
__global__ __launch_bounds__(256) void k_aggregate_pl(const ushort* __restrict__ hP,
                                                      const int* __restrict__ off,
                                                      const int* __restrict__ slist,
                                                      ushort* __restrict__ aggP) {
  int node = blockIdx.x * 4 + (threadIdx.x >> 6);
  if (node >= NN) return;
  int lane = threadIdx.x & 63;
  bool act = lane < 50;
  const uint4* hb = reinterpret_cast<const uint4*>(hP);
  float a[8] = {};
  int beg = off[node], end = off[node + 1];
  int p = beg;
#define ACC8(q)                                                   \
  {                                                               \
    a[0] += __uint_as_float((q).x << 16);                         \
    a[1] += __uint_as_float((q).x & 0xffff0000u);                 \
    a[2] += __uint_as_float((q).y << 16);                         \
    a[3] += __uint_as_float((q).y & 0xffff0000u);                 \
    a[4] += __uint_as_float((q).z << 16);                         \
    a[5] += __uint_as_float((q).z & 0xffff0000u);                 \
    a[6] += __uint_as_float((q).w << 16);                         \
    a[7] += __uint_as_float((q).w & 0xffff0000u);                 \
  }
  for (; p + 3 < end; p += 4) {
    int s0 = slist[p], s1 = slist[p + 1], s2 = slist[p + 2], s3 = slist[p + 3];
    if (act) {
      uint4 q0 = hb[(size_t)s0 * 50 + lane];
      uint4 q1 = hb[(size_t)s1 * 50 + lane];
      uint4 q2 = hb[(size_t)s2 * 50 + lane];
      uint4 q3 = hb[(size_t)s3 * 50 + lane];
      ACC8(q0) ACC8(q1) ACC8(q2) ACC8(q3)
    }
  }
  for (; p < end; ++p) {
    int s = slist[p];
    if (act) {
      uint4 q = hb[(size_t)s * 50 + lane];
      ACC8(q)
    }
  }
#undef ACC8
  float tot[8];
#pragma unroll
  for (int j = 0; j < 8; ++j) tot[j] = a[j] + __shfl_xor(a[j], 1);
  if (act) {
    uint w[8];
#pragma unroll
    for (int j = 0; j < 8; ++j) w[j] = packf(tot[j]);
    uint4 o;
    if ((lane & 1) == 0) {   // hi plane
      o.x = (w[0] >> 16) | (w[1] & 0xffff0000u);
      o.y = (w[2] >> 16) | (w[3] & 0xffff0000u);
      o.z = (w[4] >> 16) | (w[5] & 0xffff0000u);
      o.w = (w[6] >> 16) | (w[7] & 0xffff0000u);
    } else {                 // lo plane
      o.x = (w[0] & 0xffffu) | (w[1] << 16);
      o.y = (w[2] & 0xffffu) | (w[3] << 16);
      o.z = (w[4] & 0xffffu) | (w[5] << 16);
      o.w = (w[6] & 0xffffu) | (w[7] << 16);
    }
    reinterpret_cast<uint4*>(aggP)[(size_t)node * 50 + lane] = o;
  }
}

// ---------------- fused MFMA GRU step (planes, 32 rows/wave, 32 cols) -------
// Block: 256 thr (4 waves). B slice (6 mats x 25 chunks x 32 cols, bf16)
// resident in LDS (75KB -> 2 blocks/CU). A: direct global->reg plane loads
// (zero unpack VALU), dbuf. Block loops over 6 panels of 128 rows; 1 barrier.
#define NPAN 391            // ceil(NN/128)
#define PPC 6
#define NCHK 66             // 66*6 = 396 >= 391
#define NCOLB 7
#define GRIDF 462           // 7*66; swizzle q=57 r=6

#define MFMA16(a, b, c) __builtin_amdgcn_mfma_f32_16x16x32_bf16(a, b, c, 0, 0, 0)

__global__ __launch_bounds__(256, 2) void k_fused_mfma(
    const ushort* __restrict__ aggP, const ushort* __restrict__ hP,
    const ushort* __restrict__ wcB, const ushort* __restrict__ whB,
    const float* __restrict__ b_ih, const float* __restrict__ b_hh,
    ushort* __restrict__ hnP) {
  __shared__ uint4 Bb[6][25][32];   // 75 KB

  int tid = threadIdx.x;
  int lane = tid & 63;
  int wv = tid >> 6;          // 0..3
  int lr = lane & 15;
  int kc = lane >> 4;         // 0..3

  // XCD-aware bijective swizzle (m204): nwg=462, q=57, r=6
  int x = blockIdx.x & 7, ii = blockIdx.x >> 3;
  int work = (x < 6 ? x * 58 : 348 + (x - 6) * 57) + ii;
  int chunk = work / NCOLB;
  int col = work - chunk * NCOLB;
  int cc0 = col * 32;

  // ---- stage B once: 6*25*32 = 4800 uint4 units via global_load_lds ----
  {
    uint4* BbF = &Bb[0][0][0];
    for (int i2 = 0; i2 < 19; ++i2) {
      int u = tid + i2 * 256;
      if (u < 4800) {
        int mat = u / 800;
        int rem = u - mat * 800;
        int ch = rem >> 5;
        int c = rem & 31;
        int gc = cc0 + c; if (gc > 199) gc = 199;
        const ushort* wsrc = (mat & 1) ? whB : wcB;
        GLL16(wsrc + (size_t)((mat >> 1) * DIM + gc) * DIM + ch * 8, BbF + u);
      }
    }
  }
  __syncthreads();   // the ONLY block-wide barrier

  for (int j = 0; j < PPC; ++j) {
    int p = chunk * PPC + j;
    if (p >= NPAN) break;
    int prow0 = p * 128;
    int r0 = prow0 + wv * 32 + lr;
    int r1 = r0 + 16;
    int rc0 = r0 < NN ? r0 : NN - 1;
    int rc1 = r1 < NN ? r1 : NN - 1;
    const ushort* a0 = aggP + (size_t)rc0 * ROWW;
    const ushort* a1 = aggP + (size_t)rc1 * ROWW;
    const ushort* h0 = hP + (size_t)rc0 * ROWW;
    const ushort* h1 = hP + (size_t)rc1 * ROWW;

    f32x4 acc[3][2][2][2] = {};   // [gate][mat 0=agg,1=h][rf][ct]
    uint4 aq[2][2][2][2];         // [dbuf][mat][rf][plane]

#define LDA(d, t)                                                              \
  {                                                                            \
    const bool v_ = ((t) < 6) || (kc == 0);                                    \
    const int of_ = (v_ ? ((t) * 4 + kc) : 0) << 4;                            \
    const uint4 z_ = make_uint4(0, 0, 0, 0);                                   \
    aq[d][0][0][0] = v_ ? *reinterpret_cast<const uint4*>(a0 + of_) : z_;      \
    aq[d][0][0][1] = v_ ? *reinterpret_cast<const uint4*>(a0 + of_ + 8) : z_;  \
    aq[d][0][1][0] = v_ ? *reinterpret_cast<const uint4*>(a1 + of_) : z_;      \
    aq[d][0][1][1] = v_ ? *reinterpret_cast<const uint4*>(a1 + of_ + 8) : z_;  \
    aq[d][1][0][0] = v_ ? *reinterpret_cast<const uint4*>(h0 + of_) : z_;      \
    aq[d][1][0][1] = v_ ? *reinterpret_cast<const uint4*>(h0 + of_ + 8) : z_;  \
    aq[d][1][1][0] = v_ ? *reinterpret_cast<const uint4*>(h1 + of_) : z_;      \
    aq[d][1][1][1] = v_ ? *reinterpret_cast<const uint4*>(h1 + of_ + 8) : z_;  \
  }

    LDA(0, 0)
#pragma unroll
    for (int t = 0; t < 7; ++t) {
      const int cur = t & 1, nxt = cur ^ 1;
      if (t < 6) LDA(nxt, t + 1)
      int bch = t * 4 + kc; if (bch > 24) bch = 24;
#pragma unroll
      for (int g = 0; g < 3; ++g) {
#pragma unroll
        for (int ct = 0; ct < 2; ++ct) {
          short8 b1 = *reinterpret_cast<const short8*>(&Bb[g * 2 + 0][bch][ct * 16 + lr]);
          short8 b2 = *reinterpret_cast<const short8*>(&Bb[g * 2 + 1][bch][ct * 16 + lr]);
#pragma unroll
          for (int rf = 0; rf < 2; ++rf) {
            acc[g][0][rf][ct] = MFMA16(s8(aq[cur][0][rf][0]), b1, acc[g][0][rf][ct]);
            acc[g][0][rf][ct] = MFMA16(s8(aq[cur][0][rf][1]), b1, acc[g][0][rf][ct]);
            acc[g][1][rf][ct] = MFMA16(s8(aq[cur][1][rf][0]), b2, acc[g][1][rf][ct]);
            acc[g][1][rf][ct] = MFMA16(s8(aq[cur][1][rf][1]), b2, acc[g][1][rf][ct]);
          }
        }
      }
    }
#undef LDA

    // ---- epilogue: GRU gates for this wave's 32x32 tile ----
#pragma unroll
    for (int ct = 0; ct < 2; ++ct) {
      int c = cc0 + ct * 16 + lr;
      if (c >= DIM) continue;
      float bir = b_ih[c], biz = b_ih[DIM + c], bin = b_ih[2 * DIM + c];
      float bhr = b_hh[c], bhz = b_hh[DIM + c], bhn = b_hh[2 * DIM + c];
      int coff = ((c >> 3) << 4) + (c & 7);
#pragma unroll
      for (int rf = 0; rf < 2; ++rf) {
#pragma unroll
        for (int qq = 0; qq < 4; ++qq) {
          int r_ = prow0 + wv * 32 + rf * 16 + kc * 4 + qq;
          if (r_ >= NN) continue;
          size_t base = (size_t)r_ * ROWW + coff;
          float gir = acc[0][0][rf][ct][qq] + bir;
          float giz = acc[1][0][rf][ct][qq] + biz;
          float gin = acc[2][0][rf][ct][qq] + bin;
          float ghr = acc[0][1][rf][ct][qq] + bhr;
          float ghz = acc[1][1][rf][ct][qq] + bhz;
          float ghn = acc[2][1][rf][ct][qq] + bhn;
          float rr = 1.f / (1.f + __expf(-(gir + ghr)));
          float zz = 1.f / (1.f + __expf(-(giz + ghz)));
          float nn = tanhf(gin + rr * ghn);
          float hv = bfu(hP[base]) + bfu(hP[base + 8]);
          uint w = packf((1.f - zz) * nn + zz * hv);
          hnP[base] = (ushort)(w >> 16);
          hnP[base + 8] = (ushort)(w & 0xffffu);
        }
      }
    }
  }
}

// ---------------- relu + segment_max pooling (plane format) ----------------
__global__ __launch_bounds__(256) void k_pool(const ushort* __restrict__ hP,
                                              const int* __restrict__ batch,
                                              float* __restrict__ pooled) {
  int i = blockIdx.x;
  int j = threadIdx.x;
  if (j < DIM) {
    int g = batch[i];
    size_t base = (size_t)i * ROWW + ((j >> 3) << 4) + (j & 7);
    float v = bfu(hP[base]) + bfu(hP[base + 8]);
    v = v > 0.f ? v : 0.f;
    atomicMax((int*)&pooled[(size_t)g * DIM + j], __float_as_int(v));
  }
}

__global__ __launch_bounds__(256) void k_classify(const float* __restrict__ pooled,
                                                  const float* __restrict__ w,
                                                  const float* __restrict__ b,
                                                  float* __restrict__ out) {
  __shared__ float r0[256], r1[256];
  int g = blockIdx.x;
  int j = threadIdx.x;
  float p = (j < DIM) ? pooled[(size_t)g * DIM + j] : 0.f;
  r0[j] = (j < DIM) ? p * w[j] : 0.f;
  r1[j] = (j < DIM) ? p * w[DIM + j] : 0.f;
  __syncthreads();
  for (int d = 128; d > 0; d >>= 1) {
    if (j < d) { r0[j] += r0[j + d]; r1[j] += r1[j + d]; }
    __syncthreads();
  }
  if (j == 0) {
    out[g * 2 + 0] = 1.f / (1.f + expf(-(r0[0] + b[0])));
    out[g * 2 + 1] = 1.f / (1.f + expf(-(r1[0] + b[1])));
  }
}

// ---------------- host ----------------
extern "C" void kernel_launch(void* const* d_in, const int* in_sizes, int n_in,
                              void* d_out, int out_size, void* d_ws, size_t ws_size,
                              hipStream_t stream) {
  const float* x = (const float*)d_in[0];
  const int* edge_index = (const int*)d_in[1];
  const int* batch = (const int*)d_in[2];
  const float* ggnn_w = (const float*)d_in[3];
  const float* w_ih = (const float*)d_in[4];
  const float* w_hh = (const float*)d_in[5];
  const float* b_ih = (const float*)d_in[6];
  const float* b_hh = (const float*)d_in[7];
  const float* cls_w = (const float*)d_in[8];
  const float* cls_b = (const float*)d_in[9];
  float* out = (float*)d_out;

  const int* src = edge_index;       // edge_index[0]
  const int* dst = edge_index + NE;  // edge_index[1]

  char* wsb = (char*)d_ws;
  size_t off = 0;
  auto alloc = [&](size_t bytes) -> void* {
    void* p = wsb + off;
    off += (bytes + 255) & ~(size_t)255;
    return p;
  };
  ushort* hPA = (ushort*)alloc((size_t)NN * ROWW * 2);   // 40 MB
  ushort* hPB = (ushort*)alloc((size_t)NN * ROWW * 2);   // 40 MB
  ushort* aggP = (ushort*)alloc((size_t)NN * ROWW * 2);  // 40 MB
  float* Wc_tmp = (float*)alloc((size_t)DIM * 3 * DIM * 4);
  ushort* wcB = (ushort*)alloc((size_t)NSTEPS * 3 * DIM * DIM * 2);  // 1.44 MB
  ushort* whB = (ushort*)alloc((size_t)3 * DIM * DIM * 2);           // 240 KB
  float* pooled = (float*)alloc((size_t)NG * DIM * 4);
  int* indeg = (int*)alloc((size_t)NN * 4);
  int* offs = (int*)alloc((size_t)(NN + 1) * 4);
  int* slist = (int*)alloc((size_t)NE * 4);
  if (off > ws_size) return;  // fail loud (absmax) instead of faulting

  // h0 = planes(x)
  k_pack_planes<<<2048, 256, 0, stream>>>(x, hPA, NN * 25);

  // CSR build (dst -> src list)
  k_zero_i32<<<196, 256, 0, stream>>>(indeg, NN);
  k_hist<<<(NE + 255) / 256, 256, 0, stream>>>(dst, indeg, NE);
  k_scan<<<1, 1024, 0, stream>>>(indeg, offs, NN);
  k_copy_i32<<<196, 256, 0, stream>>>(offs, indeg, NN);
  k_scatter<<<(NE + 255) / 256, 256, 0, stream>>>(dst, src, indeg, slist, NE);

  // weights: Wc[s] = ggnn_w[s] @ w_ih^T -> bf16 [600][200]; whB = bf16(w_hh)
  {
    dim3 g((3 * DIM + GBN - 1) / GBN, (DIM + GBM - 1) / GBM);
    for (int s = 0; s < NSTEPS; ++s) {
      k_gemm_bt<<<g, 256, 0, stream>>>(ggnn_w + (size_t)s * DIM * DIM, w_ih, Wc_tmp,
                                       DIM, 3 * DIM, DIM);
      k_pack_wcT<<<(600 * DIM + 255) / 256, 256, 0, stream>>>(
          Wc_tmp, wcB + (size_t)s * 3 * DIM * DIM);
    }
    k_pack_bf<<<512, 256, 0, stream>>>(w_hh, whB, 3 * DIM * DIM);
  }

  ushort* hcur = hPA;
  ushort* hnext = hPB;
  for (int s = 0; s < NSTEPS; ++s) {
    k_aggregate_pl<<<(NN + 3) / 4, 256, 0, stream>>>(hcur, offs, slist, aggP);
    k_fused_mfma<<<GRIDF, 256, 0, stream>>>(aggP, hcur,
                                            wcB + (size_t)s * 3 * DIM * DIM,
                                            whB, b_ih, b_hh, hnext);
    ushort* t = hcur; hcur = hnext; hnext = t;
  }

  k_zero_f32<<<200, 256, 0, stream>>>(pooled, NG * DIM);
  k_pool<<<NN, 256, 0, stream>>>(hcur, batch, pooled);
  k_classify<<<NG, 256, 0, stream>>>(pooled, cls_w, cls_b, out);
}

// Round 10
// 1043.750 us; speedup vs baseline: 1.2815x; 1.2572x over previous
//
#include <hip/hip_runtime.h>
#include <cstdint>
#include <cstddef>

#define NN 50000
#define NE 400000
#define NG 256
#define DIM 200
#define NSTEPS 6

typedef unsigned int uint;
typedef unsigned short ushort;
typedef __attribute__((ext_vector_type(8))) short short8;
typedef __attribute__((ext_vector_type(4))) float f32x4;

#define GLL16(gsrc, ldst)                                                        \
  __builtin_amdgcn_global_load_lds(                                              \
      (const __attribute__((address_space(1))) void*)(gsrc),                     \
      (__attribute__((address_space(3))) void*)(ldst), 16, 0, 0)

__device__ __forceinline__ float bfu(ushort u) { return __uint_as_float((uint)u << 16); }
__device__ __forceinline__ uint packf(float v) {   // (hi_bf16<<16)|lo_bf16, RN-even
  uint u = __float_as_uint(v);
  uint t = u + 0x7fffu + ((u >> 16) & 1u);
  uint hb = t & 0xffff0000u;
  float lo = v - __uint_as_float(hb);
  uint ul = __float_as_uint(lo);
  uint t2 = ul + 0x7fffu + ((ul >> 16) & 1u);
  return hb | (t2 >> 16);
}
__device__ __forceinline__ ushort bf16rn(float v) {
  uint u = __float_as_uint(v);
  return (ushort)((u + 0x7fffu + ((u >> 16) & 1u)) >> 16);
}

// ---------------- utility kernels ----------------
__global__ void k_zero_i32(int* __restrict__ p, int n) {
  for (int i = blockIdx.x * blockDim.x + threadIdx.x; i < n; i += gridDim.x * blockDim.x)
    p[i] = 0;
}
__global__ void k_zero_f32(float* __restrict__ p, int n) {
  for (int i = blockIdx.x * blockDim.x + threadIdx.x; i < n; i += gridDim.x * blockDim.x)
    p[i] = 0.f;
}
__global__ void k_copy_i32(const int* __restrict__ a, int* __restrict__ b, int n) {
  for (int i = blockIdx.x * blockDim.x + threadIdx.x; i < n; i += gridDim.x * blockDim.x)
    b[i] = a[i];
}
__global__ void k_hist(const int* __restrict__ dst, int* __restrict__ cnt, int nE) {
  int e = blockIdx.x * blockDim.x + threadIdx.x;
  if (e < nE) atomicAdd(&cnt[dst[e]], 1);
}
__global__ void k_scan(const int* __restrict__ cnt, int* __restrict__ off, int n) {
  __shared__ int buf[1024];
  __shared__ int carry;
  int tid = threadIdx.x;
  if (tid == 0) { carry = 0; off[0] = 0; }
  __syncthreads();
  for (int base = 0; base < n; base += 1024) {
    int i = base + tid;
    int v = (i < n) ? cnt[i] : 0;
    buf[tid] = v;
    __syncthreads();
    for (int d = 1; d < 1024; d <<= 1) {
      int t = (tid >= d) ? buf[tid - d] : 0;
      __syncthreads();
      buf[tid] += t;
      __syncthreads();
    }
    if (i < n) off[i + 1] = carry + buf[tid];
    __syncthreads();
    if (tid == 0) carry += buf[1023];
    __syncthreads();
  }
}
__global__ void k_scatter(const int* __restrict__ dst, const int* __restrict__ src,
                          int* __restrict__ cursor, int* __restrict__ slist, int nE) {
  int e = blockIdx.x * blockDim.x + threadIdx.x;
  if (e < nE) {
    int d = dst[e];
    int pos = atomicAdd(&cursor[d], 1);
    slist[pos] = src[e];
  }
}

// fp32 -> split bf16 arrays (hi = operand plane, lo = residual for exact state)
__global__ void k_pack_split(const float* __restrict__ x, ushort* __restrict__ hHi,
                             ushort* __restrict__ hLo, int n8) {
  for (int i = blockIdx.x * blockDim.x + threadIdx.x; i < n8;
       i += gridDim.x * blockDim.x) {
    const float* s = x + (size_t)i * 8;
    uint hi[4], lo[4];
#pragma unroll
    for (int j = 0; j < 4; ++j) {
      uint w0 = packf(s[j * 2]), w1 = packf(s[j * 2 + 1]);
      hi[j] = (w0 >> 16) | (w1 & 0xffff0000u);
      lo[j] = (w0 & 0xffffu) | (w1 << 16);
    }
    *reinterpret_cast<uint4*>(hHi + (size_t)i * 8) = make_uint4(hi[0], hi[1], hi[2], hi[3]);
    *reinterpret_cast<uint4*>(hLo + (size_t)i * 8) = make_uint4(lo[0], lo[1], lo[2], lo[3]);
  }
}

// elementwise fp32 -> bf16 ushort
__global__ void k_pack_bf(const float* __restrict__ in, ushort* __restrict__ out, int n) {
  for (int i = blockIdx.x * blockDim.x + threadIdx.x; i < n; i += gridDim.x * blockDim.x)
    out[i] = bf16rn(in[i]);
}

// transpose+pack: Wc fp32 [200][600] -> bf16 ushort [600][200]
__global__ void k_pack_wcT(const float* __restrict__ Wc, ushort* __restrict__ out) {
  int idx = blockIdx.x * blockDim.x + threadIdx.x;
  if (idx < 600 * DIM) {
    int c = idx / DIM, k = idx - c * DIM;
    out[idx] = bf16rn(Wc[(size_t)k * 600 + c]);
  }
}

// ---------------- fp32 GEMM (tiny, for Wc = W @ w_ih^T) ----------------
#define GBM 64
#define GBN 64
#define GBK 8
__global__ __launch_bounds__(256) void k_gemm_bt(const float* __restrict__ A,
                                                 const float* __restrict__ B,
                                                 float* __restrict__ C,
                                                 int M, int N, int K) {
  __shared__ __align__(16) float As[GBK][GBM];
  __shared__ __align__(16) float Bs[GBK][GBN];
  int tid = threadIdx.x;
  int row0 = blockIdx.y * GBM;
  int col0 = blockIdx.x * GBN;
  int ty = tid >> 4, tx = tid & 15;
  float acc[4][4] = {};
  for (int k0 = 0; k0 < K; k0 += GBK) {
    {
      int r = tid >> 2;
      int kk = (tid & 3) * 2;
      int gr = row0 + r;
      float2 v = make_float2(0.f, 0.f);
      if (gr < M) v = *reinterpret_cast<const float2*>(&A[(size_t)gr * K + k0 + kk]);
      As[kk][r] = v.x; As[kk + 1][r] = v.y;
    }
    {
      int n = tid >> 2;
      int kk = (tid & 3) * 2;
      int gn = col0 + n;
      float2 v = make_float2(0.f, 0.f);
      if (gn < N) v = *reinterpret_cast<const float2*>(&B[(size_t)gn * K + k0 + kk]);
      Bs[kk][n] = v.x; Bs[kk + 1][n] = v.y;
    }
    __syncthreads();
#pragma unroll
    for (int k = 0; k < GBK; ++k) {
      float4 av = *reinterpret_cast<const float4*>(&As[k][ty * 4]);
      float4 bv = *reinterpret_cast<const float4*>(&Bs[k][tx * 4]);
      float a[4] = {av.x, av.y, av.z, av.w};
      float b[4] = {bv.x, bv.y, bv.z, bv.w};
#pragma unroll
      for (int i = 0; i < 4; ++i)
#pragma unroll
        for (int j = 0; j < 4; ++j) acc[i][j] += a[i] * b[j];
    }
    __syncthreads();
  }
#pragma unroll
  for (int i = 0; i < 4; ++i) {
    int r = row0 + ty * 4 + i;
    if (r >= M) continue;
#pragma unroll
    for (int j = 0; j < 4; ++j) {
      int c = col0 + tx * 4 + j;
      if (c < N) C[(size_t)r * N + c] = acc[i][j];
    }
  }
}

// ---------------- aggregation (hi plane only): wave per node ----------------
// Row = 25 uint4 (400B). Lanes 0..24 active; per edge one coalesced uint4.
__global__ __launch_bounds__(256) void k_aggregate_hi(const ushort* __restrict__ hHi,
                                                      const int* __restrict__ off,
                                                      const int* __restrict__ slist,
                                                      ushort* __restrict__ aggHi) {
  int node = blockIdx.x * 4 + (threadIdx.x >> 6);
  if (node >= NN) return;
  int lane = threadIdx.x & 63;
  bool act = lane < 25;
  const uint4* hb = reinterpret_cast<const uint4*>(hHi);
  float a[8] = {};
  int beg = off[node], end = off[node + 1];
  int p = beg;
#define ACC8(q)                                                   \
  {                                                               \
    a[0] += __uint_as_float((q).x << 16);                         \
    a[1] += __uint_as_float((q).x & 0xffff0000u);                 \
    a[2] += __uint_as_float((q).y << 16);                         \
    a[3] += __uint_as_float((q).y & 0xffff0000u);                 \
    a[4] += __uint_as_float((q).z << 16);                         \
    a[5] += __uint_as_float((q).z & 0xffff0000u);                 \
    a[6] += __uint_as_float((q).w << 16);                         \
    a[7] += __uint_as_float((q).w & 0xffff0000u);                 \
  }
  for (; p + 3 < end; p += 4) {
    int s0 = slist[p], s1 = slist[p + 1], s2 = slist[p + 2], s3 = slist[p + 3];
    if (act) {
      uint4 q0 = hb[(size_t)s0 * 25 + lane];
      uint4 q1 = hb[(size_t)s1 * 25 + lane];
      uint4 q2 = hb[(size_t)s2 * 25 + lane];
      uint4 q3 = hb[(size_t)s3 * 25 + lane];
      ACC8(q0) ACC8(q1) ACC8(q2) ACC8(q3)
    }
  }
  for (; p < end; ++p) {
    int s = slist[p];
    if (act) {
      uint4 q = hb[(size_t)s * 25 + lane];
      ACC8(q)
    }
  }
#undef ACC8
  if (act) {
    uint w[4];
#pragma unroll
    for (int j = 0; j < 4; ++j)
      w[j] = (uint)bf16rn(a[j * 2]) | ((uint)bf16rn(a[j * 2 + 1]) << 16);
    reinterpret_cast<uint4*>(aggHi)[(size_t)node * 25 + lane] =
        make_uint4(w[0], w[1], w[2], w[3]);
  }
}

// ---------------- fused MFMA GRU step (bf16 operands, exact h state) -------
// Block: 256 thr (4 waves), 32 rows/wave (2 row-frags), 32-col slice.
// B resident in LDS (75KB, 2 blocks/CU); A = direct 16B loads of hHi/aggHi.
#define NPAN 391            // ceil(NN/128)
#define PPC 6
#define NCHK 66             // 66*6 = 396 >= 391
#define NCOLB 7
#define GRIDF 462           // 7*66; swizzle q=57 r=6

#define MFMA16(a, b, c) __builtin_amdgcn_mfma_f32_16x16x32_bf16(a, b, c, 0, 0, 0)

__global__ __launch_bounds__(256, 2) void k_fused_mfma(
    const ushort* __restrict__ aggHi, const ushort* __restrict__ hHi,
    const ushort* __restrict__ hLo,
    const ushort* __restrict__ wcB, const ushort* __restrict__ whB,
    const float* __restrict__ b_ih, const float* __restrict__ b_hh,
    ushort* __restrict__ hnHi, ushort* __restrict__ hnLo) {
  __shared__ uint4 Bb[6][25][32];   // 75 KB

  int tid = threadIdx.x;
  int lane = tid & 63;
  int wv = tid >> 6;          // 0..3
  int lr = lane & 15;
  int kc = lane >> 4;         // 0..3

  // XCD-aware bijective swizzle (m204): nwg=462, q=57, r=6
  int x = blockIdx.x & 7, ii = blockIdx.x >> 3;
  int work = (x < 6 ? x * 58 : 348 + (x - 6) * 57) + ii;
  int chunk = work / NCOLB;
  int col = work - chunk * NCOLB;
  int cc0 = col * 32;

  // ---- stage B once: 6*25*32 = 4800 uint4 units via global_load_lds ----
  {
    uint4* BbF = &Bb[0][0][0];
    for (int i2 = 0; i2 < 19; ++i2) {
      int u = tid + i2 * 256;
      if (u < 4800) {
        int mat = u / 800;
        int rem = u - mat * 800;
        int ch = rem >> 5;
        int c = rem & 31;
        int gc = cc0 + c; if (gc > 199) gc = 199;
        const ushort* wsrc = (mat & 1) ? whB : wcB;
        GLL16(wsrc + (size_t)((mat >> 1) * DIM + gc) * DIM + ch * 8, BbF + u);
      }
    }
  }
  __syncthreads();   // the ONLY block-wide barrier

  for (int j = 0; j < PPC; ++j) {
    int p = chunk * PPC + j;
    if (p >= NPAN) break;
    int prow0 = p * 128;
    int r0 = prow0 + wv * 32 + lr;
    int r1 = r0 + 16;
    int rc0 = r0 < NN ? r0 : NN - 1;
    int rc1 = r1 < NN ? r1 : NN - 1;
    const ushort* a0 = aggHi + (size_t)rc0 * DIM;
    const ushort* a1 = aggHi + (size_t)rc1 * DIM;
    const ushort* h0 = hHi + (size_t)rc0 * DIM;
    const ushort* h1 = hHi + (size_t)rc1 * DIM;

    f32x4 acc[3][2][2][2] = {};   // [gate][mat 0=agg,1=h][rf][ct]
    short8 aq[2][2][2];           // [dbuf][mat][rf]

#define LDA(d, t)                                                              \
  {                                                                            \
    const bool v_ = ((t) < 6) || (kc == 0);                                    \
    const int of_ = v_ ? ((t) * 32 + kc * 8) : 0;                              \
    const short8 z_ = {0, 0, 0, 0, 0, 0, 0, 0};                                \
    aq[d][0][0] = v_ ? *reinterpret_cast<const short8*>(a0 + of_) : z_;        \
    aq[d][0][1] = v_ ? *reinterpret_cast<const short8*>(a1 + of_) : z_;        \
    aq[d][1][0] = v_ ? *reinterpret_cast<const short8*>(h0 + of_) : z_;        \
    aq[d][1][1] = v_ ? *reinterpret_cast<const short8*>(h1 + of_) : z_;        \
  }

    LDA(0, 0)
#pragma unroll
    for (int t = 0; t < 7; ++t) {
      const int cur = t & 1, nxt = cur ^ 1;
      if (t < 6) LDA(nxt, t + 1)
      int bch = t * 4 + kc; if (bch > 24) bch = 24;
#pragma unroll
      for (int g = 0; g < 3; ++g) {
#pragma unroll
        for (int ct = 0; ct < 2; ++ct) {
          short8 b1 = *reinterpret_cast<const short8*>(&Bb[g * 2 + 0][bch][ct * 16 + lr]);
          short8 b2 = *reinterpret_cast<const short8*>(&Bb[g * 2 + 1][bch][ct * 16 + lr]);
#pragma unroll
          for (int rf = 0; rf < 2; ++rf) {
            acc[g][0][rf][ct] = MFMA16(aq[cur][0][rf], b1, acc[g][0][rf][ct]);
            acc[g][1][rf][ct] = MFMA16(aq[cur][1][rf], b2, acc[g][1][rf][ct]);
          }
        }
      }
    }
#undef LDA

    // ---- epilogue: GRU gates for this wave's 32x32 tile ----
#pragma unroll
    for (int ct = 0; ct < 2; ++ct) {
      int c = cc0 + ct * 16 + lr;
      if (c >= DIM) continue;
      float bir = b_ih[c], biz = b_ih[DIM + c], bin = b_ih[2 * DIM + c];
      float bhr = b_hh[c], bhz = b_hh[DIM + c], bhn = b_hh[2 * DIM + c];
#pragma unroll
      for (int rf = 0; rf < 2; ++rf) {
#pragma unroll
        for (int qq = 0; qq < 4; ++qq) {
          int r_ = prow0 + wv * 32 + rf * 16 + kc * 4 + qq;
          if (r_ >= NN) continue;
          size_t base = (size_t)r_ * DIM + c;
          float gir = acc[0][0][rf][ct][qq] + bir;
          float giz = acc[1][0][rf][ct][qq] + biz;
          float gin = acc[2][0][rf][ct][qq] + bin;
          float ghr = acc[0][1][rf][ct][qq] + bhr;
          float ghz = acc[1][1][rf][ct][qq] + bhz;
          float ghn = acc[2][1][rf][ct][qq] + bhn;
          float rr = 1.f / (1.f + __expf(-(gir + ghr)));
          float zz = 1.f / (1.f + __expf(-(giz + ghz)));
          float nn = tanhf(gin + rr * ghn);
          float hv = bfu(hHi[base]) + bfu(hLo[base]);   // exact h state
          uint w = packf((1.f - zz) * nn + zz * hv);
          hnHi[base] = (ushort)(w >> 16);
          hnLo[base] = (ushort)(w & 0xffffu);
        }
      }
    }
  }
}

// ---------------- relu + segment_max pooling ----------------
__global__ __launch_bounds__(256) void k_pool(const ushort* __restrict__ hHi,
                                              const ushort* __restrict__ hLo,
                                              const int* __restrict__ batch,
                                              float* __restrict__ pooled) {
  int i = blockIdx.x;
  int j = threadIdx.x;
  if (j < DIM) {
    int g = batch[i];
    size_t base = (size_t)i * DIM + j;
    float v = bfu(hHi[base]) + bfu(hLo[base]);
    v = v > 0.f ? v : 0.f;
    atomicMax((int*)&pooled[(size_t)g * DIM + j], __float_as_int(v));
  }
}

__global__ __launch_bounds__(256) void k_classify(const float* __restrict__ pooled,
                                                  const float* __restrict__ w,
                                                  const float* __restrict__ b,
                                                  float* __restrict__ out) {
  __shared__ float r0[256], r1[256];
  int g = blockIdx.x;
  int j = threadIdx.x;
  float p = (j < DIM) ? pooled[(size_t)g * DIM + j] : 0.f;
  r0[j] = (j < DIM) ? p * w[j] : 0.f;
  r1[j] = (j < DIM) ? p * w[DIM + j] : 0.f;
  __syncthreads();
  for (int d = 128; d > 0; d >>= 1) {
    if (j < d) { r0[j] += r0[j + d]; r1[j] += r1[j + d]; }
    __syncthreads();
  }
  if (j == 0) {
    out[g * 2 + 0] = 1.f / (1.f + expf(-(r0[0] + b[0])));
    out[g * 2 + 1] = 1.f / (1.f + expf(-(r1[0] + b[1])));
  }
}

// ---------------- host ----------------
extern "C" void kernel_launch(void* const* d_in, const int* in_sizes, int n_in,
                              void* d_out, int out_size, void* d_ws, size_t ws_size,
                              hipStream_t stream) {
  const float* x = (const float*)d_in[0];
  const int* edge_index = (const int*)d_in[1];
  const int* batch = (const int*)d_in[2];
  const float* ggnn_w = (const float*)d_in[3];
  const float* w_ih = (const float*)d_in[4];
  const float* w_hh = (const float*)d_in[5];
  const float* b_ih = (const float*)d_in[6];
  const float* b_hh = (const float*)d_in[7];
  const float* cls_w = (const float*)d_in[8];
  const float* cls_b = (const float*)d_in[9];
  float* out = (float*)d_out;

  const int* src = edge_index;       // edge_index[0]
  const int* dst = edge_index + NE;  // edge_index[1]

  char* wsb = (char*)d_ws;
  size_t off = 0;
  auto alloc = [&](size_t bytes) -> void* {
    void* p = wsb + off;
    off += (bytes + 255) & ~(size_t)255;
    return p;
  };
  ushort* hHiA = (ushort*)alloc((size_t)NN * DIM * 2);   // 20 MB
  ushort* hLoA = (ushort*)alloc((size_t)NN * DIM * 2);   // 20 MB
  ushort* hHiB = (ushort*)alloc((size_t)NN * DIM * 2);   // 20 MB
  ushort* hLoB = (ushort*)alloc((size_t)NN * DIM * 2);   // 20 MB
  ushort* aggHi = (ushort*)alloc((size_t)NN * DIM * 2);  // 20 MB
  float* Wc_tmp = (float*)alloc((size_t)DIM * 3 * DIM * 4);
  ushort* wcB = (ushort*)alloc((size_t)NSTEPS * 3 * DIM * DIM * 2);  // 1.44 MB
  ushort* whB = (ushort*)alloc((size_t)3 * DIM * DIM * 2);           // 240 KB
  float* pooled = (float*)alloc((size_t)NG * DIM * 4);
  int* indeg = (int*)alloc((size_t)NN * 4);
  int* offs = (int*)alloc((size_t)(NN + 1) * 4);
  int* slist = (int*)alloc((size_t)NE * 4);
  if (off > ws_size) return;  // fail loud (absmax) instead of faulting

  // h0 split
  k_pack_split<<<2048, 256, 0, stream>>>(x, hHiA, hLoA, NN * DIM / 8);

  // CSR build (dst -> src list)
  k_zero_i32<<<196, 256, 0, stream>>>(indeg, NN);
  k_hist<<<(NE + 255) / 256, 256, 0, stream>>>(dst, indeg, NE);
  k_scan<<<1, 1024, 0, stream>>>(indeg, offs, NN);
  k_copy_i32<<<196, 256, 0, stream>>>(offs, indeg, NN);
  k_scatter<<<(NE + 255) / 256, 256, 0, stream>>>(dst, src, indeg, slist, NE);

  // weights: Wc[s] = ggnn_w[s] @ w_ih^T -> bf16 [600][200]; whB = bf16(w_hh)
  {
    dim3 g((3 * DIM + GBN - 1) / GBN, (DIM + GBM - 1) / GBM);
    for (int s = 0; s < NSTEPS; ++s) {
      k_gemm_bt<<<g, 256, 0, stream>>>(ggnn_w + (size_t)s * DIM * DIM, w_ih, Wc_tmp,
                                       DIM, 3 * DIM, DIM);
      k_pack_wcT<<<(600 * DIM + 255) / 256, 256, 0, stream>>>(
          Wc_tmp, wcB + (size_t)s * 3 * DIM * DIM);
    }
    k_pack_bf<<<512, 256, 0, stream>>>(w_hh, whB, 3 * DIM * DIM);
  }

  ushort* hHic = hHiA;
  ushort* hLoc = hLoA;
  ushort* hHin = hHiB;
  ushort* hLon = hLoB;
  for (int s = 0; s < NSTEPS; ++s) {
    k_aggregate_hi<<<(NN + 3) / 4, 256, 0, stream>>>(hHic, offs, slist, aggHi);
    k_fused_mfma<<<GRIDF, 256, 0, stream>>>(aggHi, hHic, hLoc,
                                            wcB + (size_t)s * 3 * DIM * DIM,
                                            whB, b_ih, b_hh, hHin, hLon);
    ushort* t;
    t = hHic; hHic = hHin; hHin = t;
    t = hLoc; hLoc = hLon; hLon = t;
  }

  k_zero_f32<<<200, 256, 0, stream>>>(pooled, NG * DIM);
  k_pool<<<NN, 256, 0, stream>>>(hHic, hLoc, batch, pooled);
  k_classify<<<NG, 256, 0, stream>>>(pooled, cls_w, cls_b, out);
}

// Round 11
// 781.273 us; speedup vs baseline: 1.7120x; 1.3360x over previous
//
#include <hip/hip_runtime.h>
#include <cstdint>
#include <cstddef>

#define NN 50000
#define NE 400000
#define NG 256
#define DIM 200
#define NSTEPS 6

typedef unsigned int uint;
typedef unsigned short ushort;
typedef __attribute__((ext_vector_type(8))) short short8;
typedef __attribute__((ext_vector_type(4))) float f32x4;

#define GLL16(gsrc, ldst)                                                        \
  __builtin_amdgcn_global_load_lds(                                              \
      (const __attribute__((address_space(1))) void*)(gsrc),                     \
      (__attribute__((address_space(3))) void*)(ldst), 16, 0, 0)

__device__ __forceinline__ float bfu(ushort u) { return __uint_as_float((uint)u << 16); }
__device__ __forceinline__ uint packf(float v) {   // (hi_bf16<<16)|lo_bf16, RN-even
  uint u = __float_as_uint(v);
  uint t = u + 0x7fffu + ((u >> 16) & 1u);
  uint hb = t & 0xffff0000u;
  float lo = v - __uint_as_float(hb);
  uint ul = __float_as_uint(lo);
  uint t2 = ul + 0x7fffu + ((ul >> 16) & 1u);
  return hb | (t2 >> 16);
}
__device__ __forceinline__ ushort bf16rn(float v) {
  uint u = __float_as_uint(v);
  return (ushort)((u + 0x7fffu + ((u >> 16) & 1u)) >> 16);
}
// fast sigmoid/tanh on v_exp + v_rcp (exact limits at +-inf)
__device__ __forceinline__ float fsig(float x) {
  return __builtin_amdgcn_rcpf(1.f + __expf(-x));
}
__device__ __forceinline__ float ftanh(float x) {
  return 1.f - 2.f * __builtin_amdgcn_rcpf(__expf(2.f * x) + 1.f);
}

// ---------------- utility kernels ----------------
__global__ void k_zero_i32(int* __restrict__ p, int n) {
  for (int i = blockIdx.x * blockDim.x + threadIdx.x; i < n; i += gridDim.x * blockDim.x)
    p[i] = 0;
}
__global__ void k_zero_f32(float* __restrict__ p, int n) {
  for (int i = blockIdx.x * blockDim.x + threadIdx.x; i < n; i += gridDim.x * blockDim.x)
    p[i] = 0.f;
}
__global__ void k_copy_i32(const int* __restrict__ a, int* __restrict__ b, int n) {
  for (int i = blockIdx.x * blockDim.x + threadIdx.x; i < n; i += gridDim.x * blockDim.x)
    b[i] = a[i];
}
__global__ void k_hist(const int* __restrict__ dst, int* __restrict__ cnt, int nE) {
  int e = blockIdx.x * blockDim.x + threadIdx.x;
  if (e < nE) atomicAdd(&cnt[dst[e]], 1);
}
__global__ void k_scan(const int* __restrict__ cnt, int* __restrict__ off, int n) {
  __shared__ int buf[1024];
  __shared__ int carry;
  int tid = threadIdx.x;
  if (tid == 0) { carry = 0; off[0] = 0; }
  __syncthreads();
  for (int base = 0; base < n; base += 1024) {
    int i = base + tid;
    int v = (i < n) ? cnt[i] : 0;
    buf[tid] = v;
    __syncthreads();
    for (int d = 1; d < 1024; d <<= 1) {
      int t = (tid >= d) ? buf[tid - d] : 0;
      __syncthreads();
      buf[tid] += t;
      __syncthreads();
    }
    if (i < n) off[i + 1] = carry + buf[tid];
    __syncthreads();
    if (tid == 0) carry += buf[1023];
    __syncthreads();
  }
}
__global__ void k_scatter(const int* __restrict__ dst, const int* __restrict__ src,
                          int* __restrict__ cursor, int* __restrict__ slist, int nE) {
  int e = blockIdx.x * blockDim.x + threadIdx.x;
  if (e < nE) {
    int d = dst[e];
    int pos = atomicAdd(&cursor[d], 1);
    slist[pos] = src[e];
  }
}

// fp32 -> split bf16 arrays (hi = operand plane, lo = residual for exact state)
__global__ void k_pack_split(const float* __restrict__ x, ushort* __restrict__ hHi,
                             ushort* __restrict__ hLo, int n8) {
  for (int i = blockIdx.x * blockDim.x + threadIdx.x; i < n8;
       i += gridDim.x * blockDim.x) {
    const float* s = x + (size_t)i * 8;
    uint hi[4], lo[4];
#pragma unroll
    for (int j = 0; j < 4; ++j) {
      uint w0 = packf(s[j * 2]), w1 = packf(s[j * 2 + 1]);
      hi[j] = (w0 >> 16) | (w1 & 0xffff0000u);
      lo[j] = (w0 & 0xffffu) | (w1 << 16);
    }
    *reinterpret_cast<uint4*>(hHi + (size_t)i * 8) = make_uint4(hi[0], hi[1], hi[2], hi[3]);
    *reinterpret_cast<uint4*>(hLo + (size_t)i * 8) = make_uint4(lo[0], lo[1], lo[2], lo[3]);
  }
}

// elementwise fp32 -> bf16 ushort
__global__ void k_pack_bf(const float* __restrict__ in, ushort* __restrict__ out, int n) {
  for (int i = blockIdx.x * blockDim.x + threadIdx.x; i < n; i += gridDim.x * blockDim.x)
    out[i] = bf16rn(in[i]);
}

// ---------------- batched: wcB[s][c][k] = bf16( sum_m ggnn_w[s][k][m] * w_ih[c][m] )
#define GBM 64
#define GBN 64
#define GBK 8
__global__ __launch_bounds__(256) void k_gemm_wc(const float* __restrict__ gg,
                                                 const float* __restrict__ w_ih,
                                                 ushort* __restrict__ wcB) {
  __shared__ __align__(16) float As[GBK][GBM];
  __shared__ __align__(16) float Bs[GBK][GBN];
  int s = blockIdx.z;
  const float* A = gg + (size_t)s * DIM * DIM;   // [200][200] rows=k
  ushort* out = wcB + (size_t)s * 3 * DIM * DIM; // [600][200]
  int tid = threadIdx.x;
  int row0 = blockIdx.y * GBM;   // k
  int col0 = blockIdx.x * GBN;   // c
  int ty = tid >> 4, tx = tid & 15;
  float acc[4][4] = {};
  for (int k0 = 0; k0 < DIM; k0 += GBK) {
    {
      int r = tid >> 2;
      int kk = (tid & 3) * 2;
      int gr = row0 + r;
      float2 v = make_float2(0.f, 0.f);
      if (gr < DIM) v = *reinterpret_cast<const float2*>(&A[(size_t)gr * DIM + k0 + kk]);
      As[kk][r] = v.x; As[kk + 1][r] = v.y;
    }
    {
      int n = tid >> 2;
      int kk = (tid & 3) * 2;
      int gn = col0 + n;   // c < 600 always
      float2 v = *reinterpret_cast<const float2*>(&w_ih[(size_t)gn * DIM + k0 + kk]);
      Bs[kk][n] = v.x; Bs[kk + 1][n] = v.y;
    }
    __syncthreads();
#pragma unroll
    for (int k = 0; k < GBK; ++k) {
      float4 av = *reinterpret_cast<const float4*>(&As[k][ty * 4]);
      float4 bv = *reinterpret_cast<const float4*>(&Bs[k][tx * 4]);
      float a[4] = {av.x, av.y, av.z, av.w};
      float b[4] = {bv.x, bv.y, bv.z, bv.w};
#pragma unroll
      for (int i = 0; i < 4; ++i)
#pragma unroll
        for (int j = 0; j < 4; ++j) acc[i][j] += a[i] * b[j];
    }
    __syncthreads();
  }
#pragma unroll
  for (int i = 0; i < 4; ++i) {
    int r = row0 + ty * 4 + i;
    if (r >= DIM) continue;
#pragma unroll
    for (int j = 0; j < 4; ++j) {
      int c = col0 + tx * 4 + j;
      out[(size_t)c * DIM + r] = bf16rn(acc[i][j]);   // transposed store
    }
  }
}

// ---------------- aggregation: 2 nodes per wave (32-lane halves) ----------------
// Row = 25 uint4 (400B). Per half-wave lanes 0..24 active; 4-deep edge unroll.
__global__ __launch_bounds__(256) void k_aggregate_hi(const ushort* __restrict__ hHi,
                                                      const int* __restrict__ off,
                                                      const int* __restrict__ slist,
                                                      ushort* __restrict__ aggHi) {
  int wid = blockIdx.x * 4 + (threadIdx.x >> 6);
  int half = (threadIdx.x >> 5) & 1;
  int node = wid * 2 + half;
  int lane32 = threadIdx.x & 31;
  bool nok = node < NN;
  bool act = (lane32 < 25) && nok;
  const uint4* hb = reinterpret_cast<const uint4*>(hHi);
  float a[8] = {};
  int beg = 0, end = 0;
  if (nok) { beg = off[node]; end = off[node + 1]; }
  int p = beg;
#define ACC8(q)                                                   \
  {                                                               \
    a[0] += __uint_as_float((q).x << 16);                         \
    a[1] += __uint_as_float((q).x & 0xffff0000u);                 \
    a[2] += __uint_as_float((q).y << 16);                         \
    a[3] += __uint_as_float((q).y & 0xffff0000u);                 \
    a[4] += __uint_as_float((q).z << 16);                         \
    a[5] += __uint_as_float((q).z & 0xffff0000u);                 \
    a[6] += __uint_as_float((q).w << 16);                         \
    a[7] += __uint_as_float((q).w & 0xffff0000u);                 \
  }
  for (; p + 3 < end; p += 4) {
    int s0 = slist[p], s1 = slist[p + 1], s2 = slist[p + 2], s3 = slist[p + 3];
    if (act) {
      uint4 q0 = hb[(size_t)s0 * 25 + lane32];
      uint4 q1 = hb[(size_t)s1 * 25 + lane32];
      uint4 q2 = hb[(size_t)s2 * 25 + lane32];
      uint4 q3 = hb[(size_t)s3 * 25 + lane32];
      ACC8(q0) ACC8(q1) ACC8(q2) ACC8(q3)
    }
  }
  for (; p < end; ++p) {
    int s = slist[p];
    if (act) {
      uint4 q = hb[(size_t)s * 25 + lane32];
      ACC8(q)
    }
  }
#undef ACC8
  if (act) {
    uint w[4];
#pragma unroll
    for (int j = 0; j < 4; ++j)
      w[j] = (uint)bf16rn(a[j * 2]) | ((uint)bf16rn(a[j * 2 + 1]) << 16);
    reinterpret_cast<uint4*>(aggHi)[(size_t)node * 25 + lane32] =
        make_uint4(w[0], w[1], w[2], w[3]);
  }
}

// ---------------- fused MFMA GRU step (bf16 operands, exact h state) -------
// Block: 256 thr (4 waves), 32 rows/wave (2 row-frags), 32-col slice.
// B resident in LDS (75KB, 2 blocks/CU); A = direct 16B loads, 2-deep prefetch.
#define NPAN 391            // ceil(NN/128)
#define PPC 6
#define NCHK 66             // 66*6 = 396 >= 391
#define NCOLB 7
#define GRIDF 462           // 7*66; swizzle q=57 r=6

#define MFMA16(a, b, c) __builtin_amdgcn_mfma_f32_16x16x32_bf16(a, b, c, 0, 0, 0)

__global__ __launch_bounds__(256, 2) void k_fused_mfma(
    const ushort* __restrict__ aggHi, const ushort* __restrict__ hHi,
    const ushort* __restrict__ hLo,
    const ushort* __restrict__ wcB, const ushort* __restrict__ whB,
    const float* __restrict__ b_ih, const float* __restrict__ b_hh,
    ushort* __restrict__ hnHi, ushort* __restrict__ hnLo) {
  __shared__ uint4 Bb[6][25][32];   // 75 KB

  int tid = threadIdx.x;
  int lane = tid & 63;
  int wv = tid >> 6;          // 0..3
  int lr = lane & 15;
  int kc = lane >> 4;         // 0..3

  // XCD-aware bijective swizzle (m204): nwg=462, q=57, r=6
  int x = blockIdx.x & 7, ii = blockIdx.x >> 3;
  int work = (x < 6 ? x * 58 : 348 + (x - 6) * 57) + ii;
  int chunk = work / NCOLB;
  int col = work - chunk * NCOLB;
  int cc0 = col * 32;

  // ---- stage B once: 6*25*32 = 4800 uint4 units via global_load_lds ----
  {
    uint4* BbF = &Bb[0][0][0];
    for (int i2 = 0; i2 < 19; ++i2) {
      int u = tid + i2 * 256;
      if (u < 4800) {
        int mat = u / 800;
        int rem = u - mat * 800;
        int ch = rem >> 5;
        int c = rem & 31;
        int gc = cc0 + c; if (gc > 199) gc = 199;
        const ushort* wsrc = (mat & 1) ? whB : wcB;
        GLL16(wsrc + (size_t)((mat >> 1) * DIM + gc) * DIM + ch * 8, BbF + u);
      }
    }
  }
  __syncthreads();   // the ONLY block-wide barrier

  for (int j = 0; j < PPC; ++j) {
    int p = chunk * PPC + j;
    if (p >= NPAN) break;
    int prow0 = p * 128;
    int r0 = prow0 + wv * 32 + lr;
    int r1 = r0 + 16;
    int rc0 = r0 < NN ? r0 : NN - 1;
    int rc1 = r1 < NN ? r1 : NN - 1;
    const ushort* a0 = aggHi + (size_t)rc0 * DIM;
    const ushort* a1 = aggHi + (size_t)rc1 * DIM;
    const ushort* h0 = hHi + (size_t)rc0 * DIM;
    const ushort* h1 = hHi + (size_t)rc1 * DIM;

    f32x4 acc[3][2][2][2] = {};   // [gate][mat 0=agg,1=h][rf][ct]
    short8 aq[3][2][2];           // [ring][mat][rf], 2-deep prefetch

#define LDA(d, t)                                                              \
  {                                                                            \
    const bool v_ = ((t) < 6) || (kc == 0);                                    \
    const int of_ = v_ ? ((t) * 32 + kc * 8) : 0;                              \
    const short8 z_ = {0, 0, 0, 0, 0, 0, 0, 0};                                \
    aq[d][0][0] = v_ ? *reinterpret_cast<const short8*>(a0 + of_) : z_;        \
    aq[d][0][1] = v_ ? *reinterpret_cast<const short8*>(a1 + of_) : z_;        \
    aq[d][1][0] = v_ ? *reinterpret_cast<const short8*>(h0 + of_) : z_;        \
    aq[d][1][1] = v_ ? *reinterpret_cast<const short8*>(h1 + of_) : z_;        \
  }

    LDA(0, 0)
    LDA(1, 1)
#pragma unroll
    for (int t = 0; t < 7; ++t) {
      const int cur = t % 3;
      if (t < 5) LDA((t + 2) % 3, t + 2)
      int bch = t * 4 + kc; if (bch > 24) bch = 24;
#pragma unroll
      for (int g = 0; g < 3; ++g) {
#pragma unroll
        for (int ct = 0; ct < 2; ++ct) {
          short8 b1 = *reinterpret_cast<const short8*>(&Bb[g * 2 + 0][bch][ct * 16 + lr]);
          short8 b2 = *reinterpret_cast<const short8*>(&Bb[g * 2 + 1][bch][ct * 16 + lr]);
#pragma unroll
          for (int rf = 0; rf < 2; ++rf) {
            acc[g][0][rf][ct] = MFMA16(aq[cur][0][rf], b1, acc[g][0][rf][ct]);
            acc[g][1][rf][ct] = MFMA16(aq[cur][1][rf], b2, acc[g][1][rf][ct]);
          }
        }
      }
    }
#undef LDA

    // ---- epilogue: GRU gates for this wave's 32x32 tile (fast transcendentals) ----
#pragma unroll
    for (int ct = 0; ct < 2; ++ct) {
      int c = cc0 + ct * 16 + lr;
      if (c >= DIM) continue;
      float bir = b_ih[c], biz = b_ih[DIM + c], bin = b_ih[2 * DIM + c];
      float bhr = b_hh[c], bhz = b_hh[DIM + c], bhn = b_hh[2 * DIM + c];
#pragma unroll
      for (int rf = 0; rf < 2; ++rf) {
#pragma unroll
        for (int qq = 0; qq < 4; ++qq) {
          int r_ = prow0 + wv * 32 + rf * 16 + kc * 4 + qq;
          if (r_ >= NN) continue;
          size_t base = (size_t)r_ * DIM + c;
          float gir = acc[0][0][rf][ct][qq] + bir;
          float giz = acc[1][0][rf][ct][qq] + biz;
          float gin = acc[2][0][rf][ct][qq] + bin;
          float ghr = acc[0][1][rf][ct][qq] + bhr;
          float ghz = acc[1][1][rf][ct][qq] + bhz;
          float ghn = acc[2][1][rf][ct][qq] + bhn;
          float rr = fsig(gir + ghr);
          float zz = fsig(giz + ghz);
          float nn = ftanh(gin + rr * ghn);
          float hv = bfu(hHi[base]) + bfu(hLo[base]);   // exact h state
          uint w = packf((1.f - zz) * nn + zz * hv);
          hnHi[base] = (ushort)(w >> 16);
          hnLo[base] = (ushort)(w & 0xffffu);
        }
      }
    }
  }
}

// ---------------- relu + segment_max pooling ----------------
__global__ __launch_bounds__(256) void k_pool(const ushort* __restrict__ hHi,
                                              const ushort* __restrict__ hLo,
                                              const int* __restrict__ batch,
                                              float* __restrict__ pooled) {
  int i = blockIdx.x;
  int j = threadIdx.x;
  if (j < DIM) {
    int g = batch[i];
    size_t base = (size_t)i * DIM + j;
    float v = bfu(hHi[base]) + bfu(hLo[base]);
    v = v > 0.f ? v : 0.f;
    atomicMax((int*)&pooled[(size_t)g * DIM + j], __float_as_int(v));
  }
}

__global__ __launch_bounds__(256) void k_classify(const float* __restrict__ pooled,
                                                  const float* __restrict__ w,
                                                  const float* __restrict__ b,
                                                  float* __restrict__ out) {
  __shared__ float r0[256], r1[256];
  int g = blockIdx.x;
  int j = threadIdx.x;
  float p = (j < DIM) ? pooled[(size_t)g * DIM + j] : 0.f;
  r0[j] = (j < DIM) ? p * w[j] : 0.f;
  r1[j] = (j < DIM) ? p * w[DIM + j] : 0.f;
  __syncthreads();
  for (int d = 128; d > 0; d >>= 1) {
    if (j < d) { r0[j] += r0[j + d]; r1[j] += r1[j + d]; }
    __syncthreads();
  }
  if (j == 0) {
    out[g * 2 + 0] = 1.f / (1.f + expf(-(r0[0] + b[0])));
    out[g * 2 + 1] = 1.f / (1.f + expf(-(r1[0] + b[1])));
  }
}

// ---------------- host ----------------
extern "C" void kernel_launch(void* const* d_in, const int* in_sizes, int n_in,
                              void* d_out, int out_size, void* d_ws, size_t ws_size,
                              hipStream_t stream) {
  const float* x = (const float*)d_in[0];
  const int* edge_index = (const int*)d_in[1];
  const int* batch = (const int*)d_in[2];
  const float* ggnn_w = (const float*)d_in[3];
  const float* w_ih = (const float*)d_in[4];
  const float* w_hh = (const float*)d_in[5];
  const float* b_ih = (const float*)d_in[6];
  const float* b_hh = (const float*)d_in[7];
  const float* cls_w = (const float*)d_in[8];
  const float* cls_b = (const float*)d_in[9];
  float* out = (float*)d_out;

  const int* src = edge_index;       // edge_index[0]
  const int* dst = edge_index + NE;  // edge_index[1]

  char* wsb = (char*)d_ws;
  size_t off = 0;
  auto alloc = [&](size_t bytes) -> void* {
    void* p = wsb + off;
    off += (bytes + 255) & ~(size_t)255;
    return p;
  };
  ushort* hHiA = (ushort*)alloc((size_t)NN * DIM * 2);   // 20 MB
  ushort* hLoA = (ushort*)alloc((size_t)NN * DIM * 2);   // 20 MB
  ushort* hHiB = (ushort*)alloc((size_t)NN * DIM * 2);   // 20 MB
  ushort* hLoB = (ushort*)alloc((size_t)NN * DIM * 2);   // 20 MB
  ushort* aggHi = (ushort*)alloc((size_t)NN * DIM * 2);  // 20 MB
  ushort* wcB = (ushort*)alloc((size_t)NSTEPS * 3 * DIM * DIM * 2);  // 1.44 MB
  ushort* whB = (ushort*)alloc((size_t)3 * DIM * DIM * 2);           // 240 KB
  float* pooled = (float*)alloc((size_t)NG * DIM * 4);
  int* indeg = (int*)alloc((size_t)NN * 4);
  int* offs = (int*)alloc((size_t)(NN + 1) * 4);
  int* slist = (int*)alloc((size_t)NE * 4);
  if (off > ws_size) return;  // fail loud (absmax) instead of faulting

  // h0 split
  k_pack_split<<<2048, 256, 0, stream>>>(x, hHiA, hLoA, NN * DIM / 8);

  // CSR build (dst -> src list)
  k_zero_i32<<<196, 256, 0, stream>>>(indeg, NN);
  k_hist<<<(NE + 255) / 256, 256, 0, stream>>>(dst, indeg, NE);
  k_scan<<<1, 1024, 0, stream>>>(indeg, offs, NN);
  k_copy_i32<<<196, 256, 0, stream>>>(offs, indeg, NN);
  k_scatter<<<(NE + 255) / 256, 256, 0, stream>>>(dst, src, indeg, slist, NE);

  // weights: wcB[s] = bf16((ggnn_w[s] @ w_ih^T)^T) in ONE batched launch; whB = bf16(w_hh)
  {
    dim3 g((3 * DIM + GBN - 1) / GBN, (DIM + GBM - 1) / GBM, NSTEPS);
    k_gemm_wc<<<g, 256, 0, stream>>>(ggnn_w, w_ih, wcB);
    k_pack_bf<<<512, 256, 0, stream>>>(w_hh, whB, 3 * DIM * DIM);
  }

  ushort* hHic = hHiA;
  ushort* hLoc = hLoA;
  ushort* hHin = hHiB;
  ushort* hLon = hLoB;
  for (int s = 0; s < NSTEPS; ++s) {
    k_aggregate_hi<<<(NN / 2 + 3) / 4, 256, 0, stream>>>(hHic, offs, slist, aggHi);
    k_fused_mfma<<<GRIDF, 256, 0, stream>>>(aggHi, hHic, hLoc,
                                            wcB + (size_t)s * 3 * DIM * DIM,
                                            whB, b_ih, b_hh, hHin, hLon);
    ushort* t;
    t = hHic; hHic = hHin; hHin = t;
    t = hLoc; hLoc = hLon; hLon = t;
  }

  k_zero_f32<<<200, 256, 0, stream>>>(pooled, NG * DIM);
  k_pool<<<NN, 256, 0, stream>>>(hHic, hLoc, batch, pooled);
  k_classify<<<NG, 256, 0, stream>>>(pooled, cls_w, cls_b, out);
}

// Round 12
// 699.990 us; speedup vs baseline: 1.9108x; 1.1161x over previous
//
#include <hip/hip_runtime.h>
#include <cstdint>
#include <cstddef>

#define NN 50000
#define NE 400000
#define NG 256
#define DIM 200
#define NSTEPS 6

typedef unsigned int uint;
typedef unsigned short ushort;
typedef __attribute__((ext_vector_type(8))) short short8;
typedef __attribute__((ext_vector_type(4))) float f32x4;

#define GLL16(gsrc, ldst)                                                        \
  __builtin_amdgcn_global_load_lds(                                              \
      (const __attribute__((address_space(1))) void*)(gsrc),                     \
      (__attribute__((address_space(3))) void*)(ldst), 16, 0, 0)

__device__ __forceinline__ float bfu(ushort u) { return __uint_as_float((uint)u << 16); }
__device__ __forceinline__ uint packf(float v) {   // (hi_bf16<<16)|lo_bf16, RN-even
  uint u = __float_as_uint(v);
  uint t = u + 0x7fffu + ((u >> 16) & 1u);
  uint hb = t & 0xffff0000u;
  float lo = v - __uint_as_float(hb);
  uint ul = __float_as_uint(lo);
  uint t2 = ul + 0x7fffu + ((ul >> 16) & 1u);
  return hb | (t2 >> 16);
}
__device__ __forceinline__ ushort bf16rn(float v) {
  uint u = __float_as_uint(v);
  return (ushort)((u + 0x7fffu + ((u >> 16) & 1u)) >> 16);
}
// fast sigmoid/tanh on v_exp + v_rcp (exact limits at +-inf)
__device__ __forceinline__ float fsig(float x) {
  return __builtin_amdgcn_rcpf(1.f + __expf(-x));
}
__device__ __forceinline__ float ftanh(float x) {
  return 1.f - 2.f * __builtin_amdgcn_rcpf(__expf(2.f * x) + 1.f);
}

// ---------------- utility kernels ----------------
__global__ void k_zero_i32(int* __restrict__ p, int n) {
  for (int i = blockIdx.x * blockDim.x + threadIdx.x; i < n; i += gridDim.x * blockDim.x)
    p[i] = 0;
}
__global__ void k_zero_f32(float* __restrict__ p, int n) {
  for (int i = blockIdx.x * blockDim.x + threadIdx.x; i < n; i += gridDim.x * blockDim.x)
    p[i] = 0.f;
}
__global__ void k_hist(const int* __restrict__ dst, int* __restrict__ cnt, int nE) {
  int e = blockIdx.x * blockDim.x + threadIdx.x;
  if (e < nE) atomicAdd(&cnt[dst[e]], 1);
}

// ---- hierarchical scan: blk (196x256) -> top (1x256) -> fin (writes off+cursor)
__global__ __launch_bounds__(256) void k_scan_blk(const int* __restrict__ cnt,
                                                  int* __restrict__ incl,
                                                  int* __restrict__ bsum, int n) {
  __shared__ int buf[256];
  int i = blockIdx.x * 256 + threadIdx.x;
  int v = (i < n) ? cnt[i] : 0;
  buf[threadIdx.x] = v;
  __syncthreads();
#pragma unroll
  for (int d = 1; d < 256; d <<= 1) {
    int t = (threadIdx.x >= d) ? buf[threadIdx.x - d] : 0;
    __syncthreads();
    buf[threadIdx.x] += t;
    __syncthreads();
  }
  if (i < n) incl[i] = buf[threadIdx.x];
  if (threadIdx.x == 255) bsum[blockIdx.x] = buf[255];
}
__global__ __launch_bounds__(256) void k_scan_top(int* __restrict__ bsum, int nb) {
  __shared__ int buf[256];
  int v = (threadIdx.x < nb) ? bsum[threadIdx.x] : 0;
  buf[threadIdx.x] = v;
  __syncthreads();
#pragma unroll
  for (int d = 1; d < 256; d <<= 1) {
    int t = (threadIdx.x >= d) ? buf[threadIdx.x - d] : 0;
    __syncthreads();
    buf[threadIdx.x] += t;
    __syncthreads();
  }
  if (threadIdx.x < nb) bsum[threadIdx.x] = buf[threadIdx.x] - v;  // exclusive
}
__global__ __launch_bounds__(256) void k_scan_fin(const int* __restrict__ cnt,
                                                  const int* __restrict__ incl,
                                                  const int* __restrict__ bsum,
                                                  int* __restrict__ off,
                                                  int* __restrict__ cursor, int n) {
  int i = blockIdx.x * 256 + threadIdx.x;
  if (i < n) {
    int o = incl[i] + bsum[blockIdx.x];
    off[i + 1] = o;
    cursor[i] = o - cnt[i];
  }
  if (i == 0) off[0] = 0;
}

__global__ void k_scatter(const int* __restrict__ dst, const int* __restrict__ src,
                          int* __restrict__ cursor, int* __restrict__ slist, int nE) {
  int e = blockIdx.x * blockDim.x + threadIdx.x;
  if (e < nE) {
    int d = dst[e];
    int pos = atomicAdd(&cursor[d], 1);
    slist[pos] = src[e];
  }
}

// fp32 -> split bf16 arrays (hi = operand plane, lo = residual for exact state)
__global__ void k_pack_split(const float* __restrict__ x, ushort* __restrict__ hHi,
                             ushort* __restrict__ hLo, int n8) {
  for (int i = blockIdx.x * blockDim.x + threadIdx.x; i < n8;
       i += gridDim.x * blockDim.x) {
    const float* s = x + (size_t)i * 8;
    uint hi[4], lo[4];
#pragma unroll
    for (int j = 0; j < 4; ++j) {
      uint w0 = packf(s[j * 2]), w1 = packf(s[j * 2 + 1]);
      hi[j] = (w0 >> 16) | (w1 & 0xffff0000u);
      lo[j] = (w0 & 0xffffu) | (w1 << 16);
    }
    *reinterpret_cast<uint4*>(hHi + (size_t)i * 8) = make_uint4(hi[0], hi[1], hi[2], hi[3]);
    *reinterpret_cast<uint4*>(hLo + (size_t)i * 8) = make_uint4(lo[0], lo[1], lo[2], lo[3]);
  }
}

// elementwise fp32 -> bf16 ushort
__global__ void k_pack_bf(const float* __restrict__ in, ushort* __restrict__ out, int n) {
  for (int i = blockIdx.x * blockDim.x + threadIdx.x; i < n; i += gridDim.x * blockDim.x)
    out[i] = bf16rn(in[i]);
}

// ---------------- batched: wcB[s][c][k] = bf16( sum_m ggnn_w[s][k][m] * w_ih[c][m] )
#define GBM 64
#define GBN 64
#define GBK 8
__global__ __launch_bounds__(256) void k_gemm_wc(const float* __restrict__ gg,
                                                 const float* __restrict__ w_ih,
                                                 ushort* __restrict__ wcB) {
  __shared__ __align__(16) float As[GBK][GBM];
  __shared__ __align__(16) float Bs[GBK][GBN];
  int s = blockIdx.z;
  const float* A = gg + (size_t)s * DIM * DIM;   // [200][200] rows=k
  ushort* out = wcB + (size_t)s * 3 * DIM * DIM; // [600][200]
  int tid = threadIdx.x;
  int row0 = blockIdx.y * GBM;   // k
  int col0 = blockIdx.x * GBN;   // c
  int ty = tid >> 4, tx = tid & 15;
  float acc[4][4] = {};
  for (int k0 = 0; k0 < DIM; k0 += GBK) {
    {
      int r = tid >> 2;
      int kk = (tid & 3) * 2;
      int gr = row0 + r;
      float2 v = make_float2(0.f, 0.f);
      if (gr < DIM) v = *reinterpret_cast<const float2*>(&A[(size_t)gr * DIM + k0 + kk]);
      As[kk][r] = v.x; As[kk + 1][r] = v.y;
    }
    {
      int n = tid >> 2;
      int kk = (tid & 3) * 2;
      int gn = col0 + n;   // c < 600 always
      float2 v = *reinterpret_cast<const float2*>(&w_ih[(size_t)gn * DIM + k0 + kk]);
      Bs[kk][n] = v.x; Bs[kk + 1][n] = v.y;
    }
    __syncthreads();
#pragma unroll
    for (int k = 0; k < GBK; ++k) {
      float4 av = *reinterpret_cast<const float4*>(&As[k][ty * 4]);
      float4 bv = *reinterpret_cast<const float4*>(&Bs[k][tx * 4]);
      float a[4] = {av.x, av.y, av.z, av.w};
      float b[4] = {bv.x, bv.y, bv.z, bv.w};
#pragma unroll
      for (int i = 0; i < 4; ++i)
#pragma unroll
        for (int j = 0; j < 4; ++j) acc[i][j] += a[i] * b[j];
    }
    __syncthreads();
  }
#pragma unroll
  for (int i = 0; i < 4; ++i) {
    int r = row0 + ty * 4 + i;
    if (r >= DIM) continue;
#pragma unroll
    for (int j = 0; j < 4; ++j) {
      int c = col0 + tx * 4 + j;
      out[(size_t)c * DIM + r] = bf16rn(acc[i][j]);   // transposed store
    }
  }
}

// ---------------- aggregation: 2 nodes per wave (32-lane halves) ----------------
// Row = 25 uint4 (400B). Per half-wave lanes 0..24 active; 4-deep edge unroll.
__global__ __launch_bounds__(256) void k_aggregate_hi(const ushort* __restrict__ hHi,
                                                      const int* __restrict__ off,
                                                      const int* __restrict__ slist,
                                                      ushort* __restrict__ aggHi) {
  int wid = blockIdx.x * 4 + (threadIdx.x >> 6);
  int half = (threadIdx.x >> 5) & 1;
  int node = wid * 2 + half;
  int lane32 = threadIdx.x & 31;
  bool nok = node < NN;
  bool act = (lane32 < 25) && nok;
  const uint4* hb = reinterpret_cast<const uint4*>(hHi);
  float a[8] = {};
  int beg = 0, end = 0;
  if (nok) { beg = off[node]; end = off[node + 1]; }
  int p = beg;
#define ACC8(q)                                                   \
  {                                                               \
    a[0] += __uint_as_float((q).x << 16);                         \
    a[1] += __uint_as_float((q).x & 0xffff0000u);                 \
    a[2] += __uint_as_float((q).y << 16);                         \
    a[3] += __uint_as_float((q).y & 0xffff0000u);                 \
    a[4] += __uint_as_float((q).z << 16);                         \
    a[5] += __uint_as_float((q).z & 0xffff0000u);                 \
    a[6] += __uint_as_float((q).w << 16);                         \
    a[7] += __uint_as_float((q).w & 0xffff0000u);                 \
  }
  for (; p + 3 < end; p += 4) {
    int s0 = slist[p], s1 = slist[p + 1], s2 = slist[p + 2], s3 = slist[p + 3];
    if (act) {
      uint4 q0 = hb[(size_t)s0 * 25 + lane32];
      uint4 q1 = hb[(size_t)s1 * 25 + lane32];
      uint4 q2 = hb[(size_t)s2 * 25 + lane32];
      uint4 q3 = hb[(size_t)s3 * 25 + lane32];
      ACC8(q0) ACC8(q1) ACC8(q2) ACC8(q3)
    }
  }
  for (; p < end; ++p) {
    int s = slist[p];
    if (act) {
      uint4 q = hb[(size_t)s * 25 + lane32];
      ACC8(q)
    }
  }
#undef ACC8
  if (act) {
    uint w[4];
#pragma unroll
    for (int j = 0; j < 4; ++j)
      w[j] = (uint)bf16rn(a[j * 2]) | ((uint)bf16rn(a[j * 2 + 1]) << 16);
    reinterpret_cast<uint4*>(aggHi)[(size_t)node * 25 + lane32] =
        make_uint4(w[0], w[1], w[2], w[3]);
  }
}

// ---------------- fused MFMA GRU step (bf16 operands, exact h state) -------
// Block: 256 thr (4 waves), 32 rows/wave (2 row-frags), 32-col slice.
// B resident in LDS (75KB, 2 blocks/CU); A = direct 16B loads, 2-deep prefetch.
#define NPAN 391            // ceil(NN/128)
#define PPC 6
#define NCHK 66             // 66*6 = 396 >= 391
#define NCOLB 7
#define GRIDF 462           // 7*66; swizzle q=57 r=6

#define MFMA16(a, b, c) __builtin_amdgcn_mfma_f32_16x16x32_bf16(a, b, c, 0, 0, 0)

__global__ __launch_bounds__(256, 2) void k_fused_mfma(
    const ushort* __restrict__ aggHi, const ushort* __restrict__ hHi,
    const ushort* __restrict__ hLo,
    const ushort* __restrict__ wcB, const ushort* __restrict__ whB,
    const float* __restrict__ b_ih, const float* __restrict__ b_hh,
    ushort* __restrict__ hnHi, ushort* __restrict__ hnLo) {
  __shared__ uint4 Bb[6][25][32];   // 75 KB

  int tid = threadIdx.x;
  int lane = tid & 63;
  int wv = tid >> 6;          // 0..3
  int lr = lane & 15;
  int kc = lane >> 4;         // 0..3

  // XCD-aware bijective swizzle (m204): nwg=462, q=57, r=6
  int x = blockIdx.x & 7, ii = blockIdx.x >> 3;
  int work = (x < 6 ? x * 58 : 348 + (x - 6) * 57) + ii;
  int chunk = work / NCOLB;
  int col = work - chunk * NCOLB;
  int cc0 = col * 32;

  // ---- stage B once: 6*25*32 = 4800 uint4 units via global_load_lds ----
  {
    uint4* BbF = &Bb[0][0][0];
    for (int i2 = 0; i2 < 19; ++i2) {
      int u = tid + i2 * 256;
      if (u < 4800) {
        int mat = u / 800;
        int rem = u - mat * 800;
        int ch = rem >> 5;
        int c = rem & 31;
        int gc = cc0 + c; if (gc > 199) gc = 199;
        const ushort* wsrc = (mat & 1) ? whB : wcB;
        GLL16(wsrc + (size_t)((mat >> 1) * DIM + gc) * DIM + ch * 8, BbF + u);
      }
    }
  }
  __syncthreads();   // the ONLY block-wide barrier

  for (int j = 0; j < PPC; ++j) {
    int p = chunk * PPC + j;
    if (p >= NPAN) break;
    int prow0 = p * 128;
    int r0 = prow0 + wv * 32 + lr;
    int r1 = r0 + 16;
    int rc0 = r0 < NN ? r0 : NN - 1;
    int rc1 = r1 < NN ? r1 : NN - 1;
    const ushort* a0 = aggHi + (size_t)rc0 * DIM;
    const ushort* a1 = aggHi + (size_t)rc1 * DIM;
    const ushort* h0 = hHi + (size_t)rc0 * DIM;
    const ushort* h1 = hHi + (size_t)rc1 * DIM;

    f32x4 acc[3][2][2][2] = {};   // [gate][mat 0=agg,1=h][rf][ct]
    short8 aq[3][2][2];           // [ring][mat][rf], 2-deep prefetch

#define LDA(d, t)                                                              \
  {                                                                            \
    const bool v_ = ((t) < 6) || (kc == 0);                                    \
    const int of_ = v_ ? ((t) * 32 + kc * 8) : 0;                              \
    const short8 z_ = {0, 0, 0, 0, 0, 0, 0, 0};                                \
    aq[d][0][0] = v_ ? *reinterpret_cast<const short8*>(a0 + of_) : z_;        \
    aq[d][0][1] = v_ ? *reinterpret_cast<const short8*>(a1 + of_) : z_;        \
    aq[d][1][0] = v_ ? *reinterpret_cast<const short8*>(h0 + of_) : z_;        \
    aq[d][1][1] = v_ ? *reinterpret_cast<const short8*>(h1 + of_) : z_;        \
  }

    LDA(0, 0)
    LDA(1, 1)
#pragma unroll
    for (int t = 0; t < 7; ++t) {
      const int cur = t % 3;
      if (t < 5) LDA((t + 2) % 3, t + 2)
      int bch = t * 4 + kc; if (bch > 24) bch = 24;
#pragma unroll
      for (int g = 0; g < 3; ++g) {
#pragma unroll
        for (int ct = 0; ct < 2; ++ct) {
          short8 b1 = *reinterpret_cast<const short8*>(&Bb[g * 2 + 0][bch][ct * 16 + lr]);
          short8 b2 = *reinterpret_cast<const short8*>(&Bb[g * 2 + 1][bch][ct * 16 + lr]);
#pragma unroll
          for (int rf = 0; rf < 2; ++rf) {
            acc[g][0][rf][ct] = MFMA16(aq[cur][0][rf], b1, acc[g][0][rf][ct]);
            acc[g][1][rf][ct] = MFMA16(aq[cur][1][rf], b2, acc[g][1][rf][ct]);
          }
        }
      }
    }
#undef LDA

    // ---- epilogue: GRU gates for this wave's 32x32 tile (fast transcendentals) ----
#pragma unroll
    for (int ct = 0; ct < 2; ++ct) {
      int c = cc0 + ct * 16 + lr;
      if (c >= DIM) continue;
      float bir = b_ih[c], biz = b_ih[DIM + c], bin = b_ih[2 * DIM + c];
      float bhr = b_hh[c], bhz = b_hh[DIM + c], bhn = b_hh[2 * DIM + c];
#pragma unroll
      for (int rf = 0; rf < 2; ++rf) {
#pragma unroll
        for (int qq = 0; qq < 4; ++qq) {
          int r_ = prow0 + wv * 32 + rf * 16 + kc * 4 + qq;
          if (r_ >= NN) continue;
          size_t base = (size_t)r_ * DIM + c;
          float gir = acc[0][0][rf][ct][qq] + bir;
          float giz = acc[1][0][rf][ct][qq] + biz;
          float gin = acc[2][0][rf][ct][qq] + bin;
          float ghr = acc[0][1][rf][ct][qq] + bhr;
          float ghz = acc[1][1][rf][ct][qq] + bhz;
          float ghn = acc[2][1][rf][ct][qq] + bhn;
          float rr = fsig(gir + ghr);
          float zz = fsig(giz + ghz);
          float nn = ftanh(gin + rr * ghn);
          float hv = bfu(hHi[base]) + bfu(hLo[base]);   // exact h state
          uint w = packf((1.f - zz) * nn + zz * hv);
          hnHi[base] = (ushort)(w >> 16);
          hnLo[base] = (ushort)(w & 0xffffu);
        }
      }
    }
  }
}

// ---------------- relu + segment_max pooling ----------------
__global__ __launch_bounds__(256) void k_pool(const ushort* __restrict__ hHi,
                                              const ushort* __restrict__ hLo,
                                              const int* __restrict__ batch,
                                              float* __restrict__ pooled) {
  int i = blockIdx.x;
  int j = threadIdx.x;
  if (j < DIM) {
    int g = batch[i];
    size_t base = (size_t)i * DIM + j;
    float v = bfu(hHi[base]) + bfu(hLo[base]);
    v = v > 0.f ? v : 0.f;
    atomicMax((int*)&pooled[(size_t)g * DIM + j], __float_as_int(v));
  }
}

__global__ __launch_bounds__(256) void k_classify(const float* __restrict__ pooled,
                                                  const float* __restrict__ w,
                                                  const float* __restrict__ b,
                                                  float* __restrict__ out) {
  __shared__ float r0[256], r1[256];
  int g = blockIdx.x;
  int j = threadIdx.x;
  float p = (j < DIM) ? pooled[(size_t)g * DIM + j] : 0.f;
  r0[j] = (j < DIM) ? p * w[j] : 0.f;
  r1[j] = (j < DIM) ? p * w[DIM + j] : 0.f;
  __syncthreads();
  for (int d = 128; d > 0; d >>= 1) {
    if (j < d) { r0[j] += r0[j + d]; r1[j] += r1[j + d]; }
    __syncthreads();
  }
  if (j == 0) {
    out[g * 2 + 0] = 1.f / (1.f + expf(-(r0[0] + b[0])));
    out[g * 2 + 1] = 1.f / (1.f + expf(-(r1[0] + b[1])));
  }
}

// ---------------- host ----------------
extern "C" void kernel_launch(void* const* d_in, const int* in_sizes, int n_in,
                              void* d_out, int out_size, void* d_ws, size_t ws_size,
                              hipStream_t stream) {
  const float* x = (const float*)d_in[0];
  const int* edge_index = (const int*)d_in[1];
  const int* batch = (const int*)d_in[2];
  const float* ggnn_w = (const float*)d_in[3];
  const float* w_ih = (const float*)d_in[4];
  const float* w_hh = (const float*)d_in[5];
  const float* b_ih = (const float*)d_in[6];
  const float* b_hh = (const float*)d_in[7];
  const float* cls_w = (const float*)d_in[8];
  const float* cls_b = (const float*)d_in[9];
  float* out = (float*)d_out;

  const int* src = edge_index;       // edge_index[0]
  const int* dst = edge_index + NE;  // edge_index[1]

  char* wsb = (char*)d_ws;
  size_t off = 0;
  auto alloc = [&](size_t bytes) -> void* {
    void* p = wsb + off;
    off += (bytes + 255) & ~(size_t)255;
    return p;
  };
  ushort* hHiA = (ushort*)alloc((size_t)NN * DIM * 2);   // 20 MB
  ushort* hLoA = (ushort*)alloc((size_t)NN * DIM * 2);   // 20 MB
  ushort* hHiB = (ushort*)alloc((size_t)NN * DIM * 2);   // 20 MB
  ushort* hLoB = (ushort*)alloc((size_t)NN * DIM * 2);   // 20 MB
  ushort* aggHi = (ushort*)alloc((size_t)NN * DIM * 2);  // 20 MB
  ushort* wcB = (ushort*)alloc((size_t)NSTEPS * 3 * DIM * DIM * 2);  // 1.44 MB
  ushort* whB = (ushort*)alloc((size_t)3 * DIM * DIM * 2);           // 240 KB
  float* pooled = (float*)alloc((size_t)NG * DIM * 4);
  int* indeg = (int*)alloc((size_t)NN * 4);
  int* offs = (int*)alloc((size_t)(NN + 1) * 4);
  int* incl = (int*)alloc((size_t)NN * 4);
  int* bsum = (int*)alloc((size_t)256 * 4);
  int* cursor = (int*)alloc((size_t)NN * 4);
  int* slist = (int*)alloc((size_t)NE * 4);
  if (off > ws_size) return;  // fail loud (absmax) instead of faulting

  const int NB = (NN + 255) / 256;   // 196

  // h0 split
  k_pack_split<<<2048, 256, 0, stream>>>(x, hHiA, hLoA, NN * DIM / 8);

  // CSR build (dst -> src list): hist -> 3-kernel hierarchical scan -> scatter
  k_zero_i32<<<196, 256, 0, stream>>>(indeg, NN);
  k_hist<<<(NE + 255) / 256, 256, 0, stream>>>(dst, indeg, NE);
  k_scan_blk<<<NB, 256, 0, stream>>>(indeg, incl, bsum, NN);
  k_scan_top<<<1, 256, 0, stream>>>(bsum, NB);
  k_scan_fin<<<NB, 256, 0, stream>>>(indeg, incl, bsum, offs, cursor, NN);
  k_scatter<<<(NE + 255) / 256, 256, 0, stream>>>(dst, src, cursor, slist, NE);

  // weights: wcB[s] = bf16((ggnn_w[s] @ w_ih^T)^T) in ONE batched launch; whB = bf16(w_hh)
  {
    dim3 g((3 * DIM + GBN - 1) / GBN, (DIM + GBM - 1) / GBM, NSTEPS);
    k_gemm_wc<<<g, 256, 0, stream>>>(ggnn_w, w_ih, wcB);
    k_pack_bf<<<512, 256, 0, stream>>>(w_hh, whB, 3 * DIM * DIM);
  }

  ushort* hHic = hHiA;
  ushort* hLoc = hLoA;
  ushort* hHin = hHiB;
  ushort* hLon = hLoB;
  for (int s = 0; s < NSTEPS; ++s) {
    k_aggregate_hi<<<(NN / 2 + 3) / 4, 256, 0, stream>>>(hHic, offs, slist, aggHi);
    k_fused_mfma<<<GRIDF, 256, 0, stream>>>(aggHi, hHic, hLoc,
                                            wcB + (size_t)s * 3 * DIM * DIM,
                                            whB, b_ih, b_hh, hHin, hLon);
    ushort* t;
    t = hHic; hHic = hHin; hHin = t;
    t = hLoc; hLoc = hLon; hLon = t;
  }

  k_zero_f32<<<200, 256, 0, stream>>>(pooled, NG * DIM);
  k_pool<<<NN, 256, 0, stream>>>(hHic, hLoc, batch, pooled);
  k_classify<<<NG, 256, 0, stream>>>(pooled, cls_w, cls_b, out);
}

// Round 13
// 669.874 us; speedup vs baseline: 1.9967x; 1.0450x over previous
//
#include <hip/hip_runtime.h>
#include <cstdint>
#include <cstddef>

#define NN 50000
#define NE 400000
#define NG 256
#define DIM 200
#define NSTEPS 6

typedef unsigned int uint;
typedef unsigned short ushort;
typedef __attribute__((ext_vector_type(8))) short short8;
typedef __attribute__((ext_vector_type(4))) float f32x4;

#define GLL16(gsrc, ldst)                                                        \
  __builtin_amdgcn_global_load_lds(                                              \
      (const __attribute__((address_space(1))) void*)(gsrc),                     \
      (__attribute__((address_space(3))) void*)(ldst), 16, 0, 0)

__device__ __forceinline__ float bfu(ushort u) { return __uint_as_float((uint)u << 16); }
__device__ __forceinline__ uint packf(float v) {   // (hi_bf16<<16)|lo_bf16, RN-even
  uint u = __float_as_uint(v);
  uint t = u + 0x7fffu + ((u >> 16) & 1u);
  uint hb = t & 0xffff0000u;
  float lo = v - __uint_as_float(hb);
  uint ul = __float_as_uint(lo);
  uint t2 = ul + 0x7fffu + ((ul >> 16) & 1u);
  return hb | (t2 >> 16);
}
// hi RN-even, lo truncated (err ~2^-17 relative: invisible) - epilogue fast path
__device__ __forceinline__ uint packf_tr(float v) {
  uint u = __float_as_uint(v);
  uint t = u + 0x7fffu + ((u >> 16) & 1u);
  uint hb = t & 0xffff0000u;
  float lo = v - __uint_as_float(hb);
  return hb | (__float_as_uint(lo) >> 16);
}
__device__ __forceinline__ ushort bf16rn(float v) {
  uint u = __float_as_uint(v);
  return (ushort)((u + 0x7fffu + ((u >> 16) & 1u)) >> 16);
}
// fast sigmoid/tanh on v_exp + v_rcp (exact limits at +-inf)
__device__ __forceinline__ float fsig(float x) {
  return __builtin_amdgcn_rcpf(1.f + __expf(-x));
}
__device__ __forceinline__ float ftanh(float x) {
  return 1.f - 2.f * __builtin_amdgcn_rcpf(__expf(2.f * x) + 1.f);
}

// ---------------- utility kernels ----------------
__global__ void k_zero_i32(int* __restrict__ p, int n) {
  for (int i = blockIdx.x * blockDim.x + threadIdx.x; i < n; i += gridDim.x * blockDim.x)
    p[i] = 0;
}
__global__ void k_zero_f32(float* __restrict__ p, int n) {
  for (int i = blockIdx.x * blockDim.x + threadIdx.x; i < n; i += gridDim.x * blockDim.x)
    p[i] = 0.f;
}
__global__ void k_hist(const int* __restrict__ dst, int* __restrict__ cnt, int nE) {
  int e = blockIdx.x * blockDim.x + threadIdx.x;
  if (e < nE) atomicAdd(&cnt[dst[e]], 1);
}

// ---- hierarchical scan: blk (196x256) -> top (1x256) -> fin (writes off+cursor)
__global__ __launch_bounds__(256) void k_scan_blk(const int* __restrict__ cnt,
                                                  int* __restrict__ incl,
                                                  int* __restrict__ bsum, int n) {
  __shared__ int buf[256];
  int i = blockIdx.x * 256 + threadIdx.x;
  int v = (i < n) ? cnt[i] : 0;
  buf[threadIdx.x] = v;
  __syncthreads();
#pragma unroll
  for (int d = 1; d < 256; d <<= 1) {
    int t = (threadIdx.x >= d) ? buf[threadIdx.x - d] : 0;
    __syncthreads();
    buf[threadIdx.x] += t;
    __syncthreads();
  }
  if (i < n) incl[i] = buf[threadIdx.x];
  if (threadIdx.x == 255) bsum[blockIdx.x] = buf[255];
}
__global__ __launch_bounds__(256) void k_scan_top(int* __restrict__ bsum, int nb) {
  __shared__ int buf[256];
  int v = (threadIdx.x < nb) ? bsum[threadIdx.x] : 0;
  buf[threadIdx.x] = v;
  __syncthreads();
#pragma unroll
  for (int d = 1; d < 256; d <<= 1) {
    int t = (threadIdx.x >= d) ? buf[threadIdx.x - d] : 0;
    __syncthreads();
    buf[threadIdx.x] += t;
    __syncthreads();
  }
  if (threadIdx.x < nb) bsum[threadIdx.x] = buf[threadIdx.x] - v;  // exclusive
}
__global__ __launch_bounds__(256) void k_scan_fin(const int* __restrict__ cnt,
                                                  const int* __restrict__ incl,
                                                  const int* __restrict__ bsum,
                                                  int* __restrict__ off,
                                                  int* __restrict__ cursor, int n) {
  int i = blockIdx.x * 256 + threadIdx.x;
  if (i < n) {
    int o = incl[i] + bsum[blockIdx.x];
    off[i + 1] = o;
    cursor[i] = o - cnt[i];
  }
  if (i == 0) off[0] = 0;
}

__global__ void k_scatter(const int* __restrict__ dst, const int* __restrict__ src,
                          int* __restrict__ cursor, int* __restrict__ slist, int nE) {
  int e = blockIdx.x * blockDim.x + threadIdx.x;
  if (e < nE) {
    int d = dst[e];
    int pos = atomicAdd(&cursor[d], 1);
    slist[pos] = src[e];
  }
}

// fp32 -> split bf16 arrays (hi = operand plane, lo = residual for exact state)
__global__ void k_pack_split(const float* __restrict__ x, ushort* __restrict__ hHi,
                             ushort* __restrict__ hLo, int n8) {
  for (int i = blockIdx.x * blockDim.x + threadIdx.x; i < n8;
       i += gridDim.x * blockDim.x) {
    const float* s = x + (size_t)i * 8;
    uint hi[4], lo[4];
#pragma unroll
    for (int j = 0; j < 4; ++j) {
      uint w0 = packf(s[j * 2]), w1 = packf(s[j * 2 + 1]);
      hi[j] = (w0 >> 16) | (w1 & 0xffff0000u);
      lo[j] = (w0 & 0xffffu) | (w1 << 16);
    }
    *reinterpret_cast<uint4*>(hHi + (size_t)i * 8) = make_uint4(hi[0], hi[1], hi[2], hi[3]);
    *reinterpret_cast<uint4*>(hLo + (size_t)i * 8) = make_uint4(lo[0], lo[1], lo[2], lo[3]);
  }
}

// elementwise fp32 -> bf16 ushort
__global__ void k_pack_bf(const float* __restrict__ in, ushort* __restrict__ out, int n) {
  for (int i = blockIdx.x * blockDim.x + threadIdx.x; i < n; i += gridDim.x * blockDim.x)
    out[i] = bf16rn(in[i]);
}

// ---------------- batched: wcB[s][c][k] = bf16( sum_m ggnn_w[s][k][m] * w_ih[c][m] )
#define GBM 64
#define GBN 64
#define GBK 8
__global__ __launch_bounds__(256) void k_gemm_wc(const float* __restrict__ gg,
                                                 const float* __restrict__ w_ih,
                                                 ushort* __restrict__ wcB) {
  __shared__ __align__(16) float As[GBK][GBM];
  __shared__ __align__(16) float Bs[GBK][GBN];
  int s = blockIdx.z;
  const float* A = gg + (size_t)s * DIM * DIM;   // [200][200] rows=k
  ushort* out = wcB + (size_t)s * 3 * DIM * DIM; // [600][200]
  int tid = threadIdx.x;
  int row0 = blockIdx.y * GBM;   // k
  int col0 = blockIdx.x * GBN;   // c
  int ty = tid >> 4, tx = tid & 15;
  float acc[4][4] = {};
  for (int k0 = 0; k0 < DIM; k0 += GBK) {
    {
      int r = tid >> 2;
      int kk = (tid & 3) * 2;
      int gr = row0 + r;
      float2 v = make_float2(0.f, 0.f);
      if (gr < DIM) v = *reinterpret_cast<const float2*>(&A[(size_t)gr * DIM + k0 + kk]);
      As[kk][r] = v.x; As[kk + 1][r] = v.y;
    }
    {
      int n = tid >> 2;
      int kk = (tid & 3) * 2;
      int gn = col0 + n;   // c < 600 always
      float2 v = *reinterpret_cast<const float2*>(&w_ih[(size_t)gn * DIM + k0 + kk]);
      Bs[kk][n] = v.x; Bs[kk + 1][n] = v.y;
    }
    __syncthreads();
#pragma unroll
    for (int k = 0; k < GBK; ++k) {
      float4 av = *reinterpret_cast<const float4*>(&As[k][ty * 4]);
      float4 bv = *reinterpret_cast<const float4*>(&Bs[k][tx * 4]);
      float a[4] = {av.x, av.y, av.z, av.w};
      float b[4] = {bv.x, bv.y, bv.z, bv.w};
#pragma unroll
      for (int i = 0; i < 4; ++i)
#pragma unroll
        for (int j = 0; j < 4; ++j) acc[i][j] += a[i] * b[j];
    }
    __syncthreads();
  }
#pragma unroll
  for (int i = 0; i < 4; ++i) {
    int r = row0 + ty * 4 + i;
    if (r >= DIM) continue;
#pragma unroll
    for (int j = 0; j < 4; ++j) {
      int c = col0 + tx * 4 + j;
      out[(size_t)c * DIM + r] = bf16rn(acc[i][j]);   // transposed store
    }
  }
}

// ---------------- aggregation: 2 nodes per wave (32-lane halves) ----------------
__global__ __launch_bounds__(256) void k_aggregate_hi(const ushort* __restrict__ hHi,
                                                      const int* __restrict__ off,
                                                      const int* __restrict__ slist,
                                                      ushort* __restrict__ aggHi) {
  int wid = blockIdx.x * 4 + (threadIdx.x >> 6);
  int half = (threadIdx.x >> 5) & 1;
  int node = wid * 2 + half;
  int lane32 = threadIdx.x & 31;
  bool nok = node < NN;
  bool act = (lane32 < 25) && nok;
  const uint4* hb = reinterpret_cast<const uint4*>(hHi);
  float a[8] = {};
  int beg = 0, end = 0;
  if (nok) { beg = off[node]; end = off[node + 1]; }
  int p = beg;
#define ACC8(q)                                                   \
  {                                                               \
    a[0] += __uint_as_float((q).x << 16);                         \
    a[1] += __uint_as_float((q).x & 0xffff0000u);                 \
    a[2] += __uint_as_float((q).y << 16);                         \
    a[3] += __uint_as_float((q).y & 0xffff0000u);                 \
    a[4] += __uint_as_float((q).z << 16);                         \
    a[5] += __uint_as_float((q).z & 0xffff0000u);                 \
    a[6] += __uint_as_float((q).w << 16);                         \
    a[7] += __uint_as_float((q).w & 0xffff0000u);                 \
  }
  for (; p + 3 < end; p += 4) {
    int s0 = slist[p], s1 = slist[p + 1], s2 = slist[p + 2], s3 = slist[p + 3];
    if (act) {
      uint4 q0 = hb[(size_t)s0 * 25 + lane32];
      uint4 q1 = hb[(size_t)s1 * 25 + lane32];
      uint4 q2 = hb[(size_t)s2 * 25 + lane32];
      uint4 q3 = hb[(size_t)s3 * 25 + lane32];
      ACC8(q0) ACC8(q1) ACC8(q2) ACC8(q3)
    }
  }
  for (; p < end; ++p) {
    int s = slist[p];
    if (act) {
      uint4 q = hb[(size_t)s * 25 + lane32];
      ACC8(q)
    }
  }
#undef ACC8
  if (act) {
    uint w[4];
#pragma unroll
    for (int j = 0; j < 4; ++j)
      w[j] = (uint)bf16rn(a[j * 2]) | ((uint)bf16rn(a[j * 2 + 1]) << 16);
    reinterpret_cast<uint4*>(aggHi)[(size_t)node * 25 + lane32] =
        make_uint4(w[0], w[1], w[2], w[3]);
  }
}

// ---------------- fused MFMA GRU step (bf16 operands, exact h state) -------
// Block: 256 thr (4 waves), 32 rows/wave (2 row-frags), 32-col slice.
// B resident in LDS (75KB, 2 blocks/CU); A = direct 16B loads, 3-deep prefetch
// (ring-4); hv state loads prefetched under last 2 ktiles' MFMA.
#define NPAN 391            // ceil(NN/128)
#define PPC 3
#define NCHK 131            // 131*3 = 393 >= 391
#define NCOLB 7
#define GRIDF 917           // 7*131; swizzle q=114 r=5

#define MFMA16(a, b, c) __builtin_amdgcn_mfma_f32_16x16x32_bf16(a, b, c, 0, 0, 0)

__global__ __launch_bounds__(256, 2) void k_fused_mfma(
    const ushort* __restrict__ aggHi, const ushort* __restrict__ hHi,
    const ushort* __restrict__ hLo,
    const ushort* __restrict__ wcB, const ushort* __restrict__ whB,
    const float* __restrict__ b_ih, const float* __restrict__ b_hh,
    ushort* __restrict__ hnHi, ushort* __restrict__ hnLo) {
  __shared__ uint4 Bb[6][25][32];   // 75 KB

  int tid = threadIdx.x;
  int lane = tid & 63;
  int wv = tid >> 6;          // 0..3
  int lr = lane & 15;
  int kc = lane >> 4;         // 0..3

  // XCD-aware bijective swizzle (m204): nwg=917, q=114, r=5
  int x = blockIdx.x & 7, ii = blockIdx.x >> 3;
  int work = (x < 5 ? x * 115 : 575 + (x - 5) * 114) + ii;
  int chunk = work / NCOLB;
  int col = work - chunk * NCOLB;
  int cc0 = col * 32;

  // ---- stage B once: 6*25*32 = 4800 uint4 units via global_load_lds ----
  {
    uint4* BbF = &Bb[0][0][0];
    for (int i2 = 0; i2 < 19; ++i2) {
      int u = tid + i2 * 256;
      if (u < 4800) {
        int mat = u / 800;
        int rem = u - mat * 800;
        int ch = rem >> 5;
        int c = rem & 31;
        int gc = cc0 + c; if (gc > 199) gc = 199;
        const ushort* wsrc = (mat & 1) ? whB : wcB;
        GLL16(wsrc + (size_t)((mat >> 1) * DIM + gc) * DIM + ch * 8, BbF + u);
      }
    }
  }
  __syncthreads();   // the ONLY block-wide barrier

  for (int j = 0; j < PPC; ++j) {
    int p = chunk * PPC + j;
    if (p >= NPAN) break;
    int prow0 = p * 128;
    int r0 = prow0 + wv * 32 + lr;
    int r1 = r0 + 16;
    int rc0 = r0 < NN ? r0 : NN - 1;
    int rc1 = r1 < NN ? r1 : NN - 1;
    const ushort* a0 = aggHi + (size_t)rc0 * DIM;
    const ushort* a1 = aggHi + (size_t)rc1 * DIM;
    const ushort* h0 = hHi + (size_t)rc0 * DIM;
    const ushort* h1 = hHi + (size_t)rc1 * DIM;

    f32x4 acc[3][2][2][2] = {};   // [gate][mat 0=agg,1=h][rf][ct]
    short8 aq[4][2][2];           // [ring4][mat][rf], 3-deep prefetch
    ushort hvh[2][2][4], hvl[2][2][4];   // prefetched h-state for epilogue

#define LDA(d, t)                                                              \
  {                                                                            \
    const bool v_ = ((t) < 6) || (kc == 0);                                    \
    const int of_ = v_ ? ((t) * 32 + kc * 8) : 0;                              \
    const short8 z_ = {0, 0, 0, 0, 0, 0, 0, 0};                                \
    aq[d][0][0] = v_ ? *reinterpret_cast<const short8*>(a0 + of_) : z_;        \
    aq[d][0][1] = v_ ? *reinterpret_cast<const short8*>(a1 + of_) : z_;        \
    aq[d][1][0] = v_ ? *reinterpret_cast<const short8*>(h0 + of_) : z_;        \
    aq[d][1][1] = v_ ? *reinterpret_cast<const short8*>(h1 + of_) : z_;        \
  }

    LDA(0, 0)
    LDA(1, 1)
    LDA(2, 2)
#pragma unroll
    for (int t = 0; t < 7; ++t) {
      const int cur = t & 3;
      if (t < 4) LDA((t + 3) & 3, t + 3)
      if (t == 5) {
        // prefetch epilogue h-state under the last two ktiles' MFMA
#pragma unroll
        for (int ct = 0; ct < 2; ++ct) {
          int c = cc0 + ct * 16 + lr; if (c > 199) c = 199;
#pragma unroll
          for (int rf = 0; rf < 2; ++rf) {
#pragma unroll
            for (int qq = 0; qq < 4; ++qq) {
              int r_ = prow0 + wv * 32 + rf * 16 + kc * 4 + qq;
              int rc = r_ < NN ? r_ : NN - 1;
              size_t base = (size_t)rc * DIM + c;
              hvh[ct][rf][qq] = hHi[base];
              hvl[ct][rf][qq] = hLo[base];
            }
          }
        }
      }
      int bch = t * 4 + kc; if (bch > 24) bch = 24;
#pragma unroll
      for (int g = 0; g < 3; ++g) {
#pragma unroll
        for (int ct = 0; ct < 2; ++ct) {
          short8 b1 = *reinterpret_cast<const short8*>(&Bb[g * 2 + 0][bch][ct * 16 + lr]);
          short8 b2 = *reinterpret_cast<const short8*>(&Bb[g * 2 + 1][bch][ct * 16 + lr]);
#pragma unroll
          for (int rf = 0; rf < 2; ++rf) {
            acc[g][0][rf][ct] = MFMA16(aq[cur][0][rf], b1, acc[g][0][rf][ct]);
            acc[g][1][rf][ct] = MFMA16(aq[cur][1][rf], b2, acc[g][1][rf][ct]);
          }
        }
      }
    }
#undef LDA

    // ---- epilogue: GRU gates for this wave's 32x32 tile ----
#pragma unroll
    for (int ct = 0; ct < 2; ++ct) {
      int c = cc0 + ct * 16 + lr;
      if (c >= DIM) continue;
      float bir = b_ih[c], biz = b_ih[DIM + c], bin = b_ih[2 * DIM + c];
      float bhr = b_hh[c], bhz = b_hh[DIM + c], bhn = b_hh[2 * DIM + c];
#pragma unroll
      for (int rf = 0; rf < 2; ++rf) {
#pragma unroll
        for (int qq = 0; qq < 4; ++qq) {
          int r_ = prow0 + wv * 32 + rf * 16 + kc * 4 + qq;
          if (r_ >= NN) continue;
          size_t base = (size_t)r_ * DIM + c;
          float gir = acc[0][0][rf][ct][qq] + bir;
          float giz = acc[1][0][rf][ct][qq] + biz;
          float gin = acc[2][0][rf][ct][qq] + bin;
          float ghr = acc[0][1][rf][ct][qq] + bhr;
          float ghz = acc[1][1][rf][ct][qq] + bhz;
          float ghn = acc[2][1][rf][ct][qq] + bhn;
          float rr = fsig(gir + ghr);
          float zz = fsig(giz + ghz);
          float nn = ftanh(gin + rr * ghn);
          float hv = bfu(hvh[ct][rf][qq]) + bfu(hvl[ct][rf][qq]);   // exact h state
          uint w = packf_tr((1.f - zz) * nn + zz * hv);
          hnHi[base] = (ushort)(w >> 16);
          hnLo[base] = (ushort)(w & 0xffffu);
        }
      }
    }
  }
}

// ---------------- relu + segment_max pooling ----------------
__global__ __launch_bounds__(256) void k_pool(const ushort* __restrict__ hHi,
                                              const ushort* __restrict__ hLo,
                                              const int* __restrict__ batch,
                                              float* __restrict__ pooled) {
  int i = blockIdx.x;
  int j = threadIdx.x;
  if (j < DIM) {
    int g = batch[i];
    size_t base = (size_t)i * DIM + j;
    float v = bfu(hHi[base]) + bfu(hLo[base]);
    v = v > 0.f ? v : 0.f;
    atomicMax((int*)&pooled[(size_t)g * DIM + j], __float_as_int(v));
  }
}

__global__ __launch_bounds__(256) void k_classify(const float* __restrict__ pooled,
                                                  const float* __restrict__ w,
                                                  const float* __restrict__ b,
                                                  float* __restrict__ out) {
  __shared__ float r0[256], r1[256];
  int g = blockIdx.x;
  int j = threadIdx.x;
  float p = (j < DIM) ? pooled[(size_t)g * DIM + j] : 0.f;
  r0[j] = (j < DIM) ? p * w[j] : 0.f;
  r1[j] = (j < DIM) ? p * w[DIM + j] : 0.f;
  __syncthreads();
  for (int d = 128; d > 0; d >>= 1) {
    if (j < d) { r0[j] += r0[j + d]; r1[j] += r1[j + d]; }
    __syncthreads();
  }
  if (j == 0) {
    out[g * 2 + 0] = 1.f / (1.f + expf(-(r0[0] + b[0])));
    out[g * 2 + 1] = 1.f / (1.f + expf(-(r1[0] + b[1])));
  }
}

// ---------------- host ----------------
extern "C" void kernel_launch(void* const* d_in, const int* in_sizes, int n_in,
                              void* d_out, int out_size, void* d_ws, size_t ws_size,
                              hipStream_t stream) {
  const float* x = (const float*)d_in[0];
  const int* edge_index = (const int*)d_in[1];
  const int* batch = (const int*)d_in[2];
  const float* ggnn_w = (const float*)d_in[3];
  const float* w_ih = (const float*)d_in[4];
  const float* w_hh = (const float*)d_in[5];
  const float* b_ih = (const float*)d_in[6];
  const float* b_hh = (const float*)d_in[7];
  const float* cls_w = (const float*)d_in[8];
  const float* cls_b = (const float*)d_in[9];
  float* out = (float*)d_out;

  const int* src = edge_index;       // edge_index[0]
  const int* dst = edge_index + NE;  // edge_index[1]

  char* wsb = (char*)d_ws;
  size_t off = 0;
  auto alloc = [&](size_t bytes) -> void* {
    void* p = wsb + off;
    off += (bytes + 255) & ~(size_t)255;
    return p;
  };
  ushort* hHiA = (ushort*)alloc((size_t)NN * DIM * 2);   // 20 MB
  ushort* hLoA = (ushort*)alloc((size_t)NN * DIM * 2);   // 20 MB
  ushort* hHiB = (ushort*)alloc((size_t)NN * DIM * 2);   // 20 MB
  ushort* hLoB = (ushort*)alloc((size_t)NN * DIM * 2);   // 20 MB
  ushort* aggHi = (ushort*)alloc((size_t)NN * DIM * 2);  // 20 MB
  ushort* wcB = (ushort*)alloc((size_t)NSTEPS * 3 * DIM * DIM * 2);  // 1.44 MB
  ushort* whB = (ushort*)alloc((size_t)3 * DIM * DIM * 2);           // 240 KB
  float* pooled = (float*)alloc((size_t)NG * DIM * 4);
  int* indeg = (int*)alloc((size_t)NN * 4);
  int* offs = (int*)alloc((size_t)(NN + 1) * 4);
  int* incl = (int*)alloc((size_t)NN * 4);
  int* bsum = (int*)alloc((size_t)256 * 4);
  int* cursor = (int*)alloc((size_t)NN * 4);
  int* slist = (int*)alloc((size_t)NE * 4);
  if (off > ws_size) return;  // fail loud (absmax) instead of faulting

  const int NB = (NN + 255) / 256;   // 196

  // h0 split
  k_pack_split<<<2048, 256, 0, stream>>>(x, hHiA, hLoA, NN * DIM / 8);

  // CSR build (dst -> src list): hist -> 3-kernel hierarchical scan -> scatter
  k_zero_i32<<<196, 256, 0, stream>>>(indeg, NN);
  k_hist<<<(NE + 255) / 256, 256, 0, stream>>>(dst, indeg, NE);
  k_scan_blk<<<NB, 256, 0, stream>>>(indeg, incl, bsum, NN);
  k_scan_top<<<1, 256, 0, stream>>>(bsum, NB);
  k_scan_fin<<<NB, 256, 0, stream>>>(indeg, incl, bsum, offs, cursor, NN);
  k_scatter<<<(NE + 255) / 256, 256, 0, stream>>>(dst, src, cursor, slist, NE);

  // weights: wcB[s] = bf16((ggnn_w[s] @ w_ih^T)^T) in ONE batched launch; whB = bf16(w_hh)
  {
    dim3 g((3 * DIM + GBN - 1) / GBN, (DIM + GBM - 1) / GBM, NSTEPS);
    k_gemm_wc<<<g, 256, 0, stream>>>(ggnn_w, w_ih, wcB);
    k_pack_bf<<<512, 256, 0, stream>>>(w_hh, whB, 3 * DIM * DIM);
  }

  ushort* hHic = hHiA;
  ushort* hLoc = hLoA;
  ushort* hHin = hHiB;
  ushort* hLon = hLoB;
  for (int s = 0; s < NSTEPS; ++s) {
    k_aggregate_hi<<<(NN / 2 + 3) / 4, 256, 0, stream>>>(hHic, offs, slist, aggHi);
    k_fused_mfma<<<GRIDF, 256, 0, stream>>>(aggHi, hHic, hLoc,
                                            wcB + (size_t)s * 3 * DIM * DIM,
                                            whB, b_ih, b_hh, hHin, hLon);
    ushort* t;
    t = hHic; hHic = hHin; hHin = t;
    t = hLoc; hLoc = hLon; hLon = t;
  }

  k_zero_f32<<<200, 256, 0, stream>>>(pooled, NG * DIM);
  k_pool<<<NN, 256, 0, stream>>>(hHic, hLoc, batch, pooled);
  k_classify<<<NG, 256, 0, stream>>>(pooled, cls_w, cls_b, out);
}

// Round 14
// 640.437 us; speedup vs baseline: 2.0884x; 1.0460x over previous
//
#include <hip/hip_runtime.h>
#include <cstdint>
#include <cstddef>

#define NN 50000
#define NE 400000
#define NG 256
#define DIM 200
#define NSTEPS 6

typedef unsigned int uint;
typedef unsigned short ushort;
typedef __attribute__((ext_vector_type(8))) short short8;
typedef __attribute__((ext_vector_type(4))) float f32x4;

#define GLL16(gsrc, ldst)                                                        \
  __builtin_amdgcn_global_load_lds(                                              \
      (const __attribute__((address_space(1))) void*)(gsrc),                     \
      (__attribute__((address_space(3))) void*)(ldst), 16, 0, 0)

__device__ __forceinline__ float bfu(ushort u) { return __uint_as_float((uint)u << 16); }
__device__ __forceinline__ uint packf(float v) {   // (hi_bf16<<16)|lo_bf16, RN-even
  uint u = __float_as_uint(v);
  uint t = u + 0x7fffu + ((u >> 16) & 1u);
  uint hb = t & 0xffff0000u;
  float lo = v - __uint_as_float(hb);
  uint ul = __float_as_uint(lo);
  uint t2 = ul + 0x7fffu + ((ul >> 16) & 1u);
  return hb | (t2 >> 16);
}
// hi RN-even, lo truncated (err ~2^-17 relative: invisible) - epilogue fast path
__device__ __forceinline__ uint packf_tr(float v) {
  uint u = __float_as_uint(v);
  uint t = u + 0x7fffu + ((u >> 16) & 1u);
  uint hb = t & 0xffff0000u;
  float lo = v - __uint_as_float(hb);
  return hb | (__float_as_uint(lo) >> 16);
}
__device__ __forceinline__ ushort bf16rn(float v) {
  uint u = __float_as_uint(v);
  return (ushort)((u + 0x7fffu + ((u >> 16) & 1u)) >> 16);
}
// fast sigmoid/tanh on v_exp + v_rcp (exact limits at +-inf)
__device__ __forceinline__ float fsig(float x) {
  return __builtin_amdgcn_rcpf(1.f + __expf(-x));
}
__device__ __forceinline__ float ftanh(float x) {
  return 1.f - 2.f * __builtin_amdgcn_rcpf(__expf(2.f * x) + 1.f);
}

// ---------------- utility kernels ----------------
__global__ void k_zero_i32(int* __restrict__ p, int n) {
  for (int i = blockIdx.x * blockDim.x + threadIdx.x; i < n; i += gridDim.x * blockDim.x)
    p[i] = 0;
}
__global__ void k_zero_f32(float* __restrict__ p, int n) {
  for (int i = blockIdx.x * blockDim.x + threadIdx.x; i < n; i += gridDim.x * blockDim.x)
    p[i] = 0.f;
}
__global__ void k_hist(const int* __restrict__ dst, int* __restrict__ cnt, int nE) {
  int e = blockIdx.x * blockDim.x + threadIdx.x;
  if (e < nE) atomicAdd(&cnt[dst[e]], 1);
}

// ---- hierarchical scan: blk (196x256) -> top (1x256) -> fin (writes off+cursor)
__global__ __launch_bounds__(256) void k_scan_blk(const int* __restrict__ cnt,
                                                  int* __restrict__ incl,
                                                  int* __restrict__ bsum, int n) {
  __shared__ int buf[256];
  int i = blockIdx.x * 256 + threadIdx.x;
  int v = (i < n) ? cnt[i] : 0;
  buf[threadIdx.x] = v;
  __syncthreads();
#pragma unroll
  for (int d = 1; d < 256; d <<= 1) {
    int t = (threadIdx.x >= d) ? buf[threadIdx.x - d] : 0;
    __syncthreads();
    buf[threadIdx.x] += t;
    __syncthreads();
  }
  if (i < n) incl[i] = buf[threadIdx.x];
  if (threadIdx.x == 255) bsum[blockIdx.x] = buf[255];
}
__global__ __launch_bounds__(256) void k_scan_top(int* __restrict__ bsum, int nb) {
  __shared__ int buf[256];
  int v = (threadIdx.x < nb) ? bsum[threadIdx.x] : 0;
  buf[threadIdx.x] = v;
  __syncthreads();
#pragma unroll
  for (int d = 1; d < 256; d <<= 1) {
    int t = (threadIdx.x >= d) ? buf[threadIdx.x - d] : 0;
    __syncthreads();
    buf[threadIdx.x] += t;
    __syncthreads();
  }
  if (threadIdx.x < nb) bsum[threadIdx.x] = buf[threadIdx.x] - v;  // exclusive
}
__global__ __launch_bounds__(256) void k_scan_fin(const int* __restrict__ cnt,
                                                  const int* __restrict__ incl,
                                                  const int* __restrict__ bsum,
                                                  int* __restrict__ off,
                                                  int* __restrict__ cursor, int n) {
  int i = blockIdx.x * 256 + threadIdx.x;
  if (i < n) {
    int o = incl[i] + bsum[blockIdx.x];
    off[i + 1] = o;
    cursor[i] = o - cnt[i];
  }
  if (i == 0) off[0] = 0;
}

__global__ void k_scatter(const int* __restrict__ dst, const int* __restrict__ src,
                          int* __restrict__ cursor, int* __restrict__ slist, int nE) {
  int e = blockIdx.x * blockDim.x + threadIdx.x;
  if (e < nE) {
    int d = dst[e];
    int pos = atomicAdd(&cursor[d], 1);
    slist[pos] = src[e];
  }
}

// fp32 -> split bf16 arrays (hi = operand plane, lo = residual for exact state)
__global__ void k_pack_split(const float* __restrict__ x, ushort* __restrict__ hHi,
                             ushort* __restrict__ hLo, int n8) {
  for (int i = blockIdx.x * blockDim.x + threadIdx.x; i < n8;
       i += gridDim.x * blockDim.x) {
    const float* s = x + (size_t)i * 8;
    uint hi[4], lo[4];
#pragma unroll
    for (int j = 0; j < 4; ++j) {
      uint w0 = packf(s[j * 2]), w1 = packf(s[j * 2 + 1]);
      hi[j] = (w0 >> 16) | (w1 & 0xffff0000u);
      lo[j] = (w0 & 0xffffu) | (w1 << 16);
    }
    *reinterpret_cast<uint4*>(hHi + (size_t)i * 8) = make_uint4(hi[0], hi[1], hi[2], hi[3]);
    *reinterpret_cast<uint4*>(hLo + (size_t)i * 8) = make_uint4(lo[0], lo[1], lo[2], lo[3]);
  }
}

// elementwise fp32 -> bf16 ushort
__global__ void k_pack_bf(const float* __restrict__ in, ushort* __restrict__ out, int n) {
  for (int i = blockIdx.x * blockDim.x + threadIdx.x; i < n; i += gridDim.x * blockDim.x)
    out[i] = bf16rn(in[i]);
}

// ---------------- batched: wcB[s][c][k] = bf16( sum_m ggnn_w[s][k][m] * w_ih[c][m] )
#define GBM 64
#define GBN 64
#define GBK 8
__global__ __launch_bounds__(256) void k_gemm_wc(const float* __restrict__ gg,
                                                 const float* __restrict__ w_ih,
                                                 ushort* __restrict__ wcB) {
  __shared__ __align__(16) float As[GBK][GBM];
  __shared__ __align__(16) float Bs[GBK][GBN];
  int s = blockIdx.z;
  const float* A = gg + (size_t)s * DIM * DIM;   // [200][200] rows=k
  ushort* out = wcB + (size_t)s * 3 * DIM * DIM; // [600][200]
  int tid = threadIdx.x;
  int row0 = blockIdx.y * GBM;   // k
  int col0 = blockIdx.x * GBN;   // c
  int ty = tid >> 4, tx = tid & 15;
  float acc[4][4] = {};
  for (int k0 = 0; k0 < DIM; k0 += GBK) {
    {
      int r = tid >> 2;
      int kk = (tid & 3) * 2;
      int gr = row0 + r;
      float2 v = make_float2(0.f, 0.f);
      if (gr < DIM) v = *reinterpret_cast<const float2*>(&A[(size_t)gr * DIM + k0 + kk]);
      As[kk][r] = v.x; As[kk + 1][r] = v.y;
    }
    {
      int n = tid >> 2;
      int kk = (tid & 3) * 2;
      int gn = col0 + n;   // c < 600 always
      float2 v = *reinterpret_cast<const float2*>(&w_ih[(size_t)gn * DIM + k0 + kk]);
      Bs[kk][n] = v.x; Bs[kk + 1][n] = v.y;
    }
    __syncthreads();
#pragma unroll
    for (int k = 0; k < GBK; ++k) {
      float4 av = *reinterpret_cast<const float4*>(&As[k][ty * 4]);
      float4 bv = *reinterpret_cast<const float4*>(&Bs[k][tx * 4]);
      float a[4] = {av.x, av.y, av.z, av.w};
      float b[4] = {bv.x, bv.y, bv.z, bv.w};
#pragma unroll
      for (int i = 0; i < 4; ++i)
#pragma unroll
        for (int j = 0; j < 4; ++j) acc[i][j] += a[i] * b[j];
    }
    __syncthreads();
  }
#pragma unroll
  for (int i = 0; i < 4; ++i) {
    int r = row0 + ty * 4 + i;
    if (r >= DIM) continue;
#pragma unroll
    for (int j = 0; j < 4; ++j) {
      int c = col0 + tx * 4 + j;
      out[(size_t)c * DIM + r] = bf16rn(acc[i][j]);   // transposed store
    }
  }
}

// ---------------- aggregation: 2 nodes per wave, 8-deep gather MLP ----------------
__global__ __launch_bounds__(256) void k_aggregate_hi(const ushort* __restrict__ hHi,
                                                      const int* __restrict__ off,
                                                      const int* __restrict__ slist,
                                                      ushort* __restrict__ aggHi) {
  int wid = blockIdx.x * 4 + (threadIdx.x >> 6);
  int half = (threadIdx.x >> 5) & 1;
  int node = wid * 2 + half;
  int lane32 = threadIdx.x & 31;
  bool nok = node < NN;
  bool act = (lane32 < 25) && nok;
  const uint4* hb = reinterpret_cast<const uint4*>(hHi);
  float a[8] = {};
  int beg = 0, end = 0;
  if (nok) { beg = off[node]; end = off[node + 1]; }
  int p = beg;
#define ACC8(q)                                                   \
  {                                                               \
    a[0] += __uint_as_float((q).x << 16);                         \
    a[1] += __uint_as_float((q).x & 0xffff0000u);                 \
    a[2] += __uint_as_float((q).y << 16);                         \
    a[3] += __uint_as_float((q).y & 0xffff0000u);                 \
    a[4] += __uint_as_float((q).z << 16);                         \
    a[5] += __uint_as_float((q).z & 0xffff0000u);                 \
    a[6] += __uint_as_float((q).w << 16);                         \
    a[7] += __uint_as_float((q).w & 0xffff0000u);                 \
  }
  for (; p + 7 < end; p += 8) {
    uint4 q[8];
    if (act) {
#pragma unroll
      for (int e = 0; e < 8; ++e) q[e] = hb[(size_t)slist[p + e] * 25 + lane32];
#pragma unroll
      for (int e = 0; e < 8; ++e) ACC8(q[e])
    }
  }
  for (; p + 3 < end; p += 4) {
    uint4 q[4];
    if (act) {
#pragma unroll
      for (int e = 0; e < 4; ++e) q[e] = hb[(size_t)slist[p + e] * 25 + lane32];
#pragma unroll
      for (int e = 0; e < 4; ++e) ACC8(q[e])
    }
  }
  for (; p < end; ++p) {
    int s = slist[p];
    if (act) {
      uint4 q = hb[(size_t)s * 25 + lane32];
      ACC8(q)
    }
  }
#undef ACC8
  if (act) {
    uint w[4];
#pragma unroll
    for (int j = 0; j < 4; ++j)
      w[j] = (uint)bf16rn(a[j * 2]) | ((uint)bf16rn(a[j * 2 + 1]) << 16);
    reinterpret_cast<uint4*>(aggHi)[(size_t)node * 25 + lane32] =
        make_uint4(w[0], w[1], w[2], w[3]);
  }
}

// ---------------- fused MFMA GRU step (bf16 operands, exact h state) -------
// Block: 256 thr (4 waves), 32 rows/wave (2 row-frags), 32-col slice.
// B resident in LDS (75KB, 2 blocks/CU); A = direct 16B loads, 3-deep prefetch;
// epilogue addressing hoisted; setprio(1) around MFMA cluster (indep waves).
#define NPAN 391            // ceil(NN/128)
#define PPC 3
#define NCHK 131            // 131*3 = 393 >= 391
#define NCOLB 7
#define GRIDF 917           // 7*131; swizzle q=114 r=5

#define MFMA16(a, b, c) __builtin_amdgcn_mfma_f32_16x16x32_bf16(a, b, c, 0, 0, 0)

__global__ __launch_bounds__(256, 2) void k_fused_mfma(
    const ushort* __restrict__ aggHi, const ushort* __restrict__ hHi,
    const ushort* __restrict__ hLo,
    const ushort* __restrict__ wcB, const ushort* __restrict__ whB,
    const float* __restrict__ b_ih, const float* __restrict__ b_hh,
    ushort* __restrict__ hnHi, ushort* __restrict__ hnLo) {
  __shared__ uint4 Bb[6][25][32];   // 75 KB

  int tid = threadIdx.x;
  int lane = tid & 63;
  int wv = tid >> 6;          // 0..3
  int lr = lane & 15;
  int kc = lane >> 4;         // 0..3

  // XCD-aware bijective swizzle (m204): nwg=917, q=114, r=5
  int x = blockIdx.x & 7, ii = blockIdx.x >> 3;
  int work = (x < 5 ? x * 115 : 575 + (x - 5) * 114) + ii;
  int chunk = work / NCOLB;
  int col = work - chunk * NCOLB;
  int cc0 = col * 32;

  // per-thread column constants (fixed across panels)
  int c0 = cc0 + lr;            // ct=0 column
  int c1 = c0 + 16;             // ct=1 column
  bool c0ok = c0 < DIM, c1ok = c1 < DIM;
  int c0c = c0ok ? c0 : DIM - 1;
  int c1c = c1ok ? c1 : DIM - 1;

  // hoisted biases (per-thread constants)
  float bias[2][6];
#pragma unroll
  for (int ct = 0; ct < 2; ++ct) {
    int c = ct ? c1c : c0c;
    bias[ct][0] = b_ih[c];           bias[ct][1] = b_ih[DIM + c];
    bias[ct][2] = b_ih[2 * DIM + c]; bias[ct][3] = b_hh[c];
    bias[ct][4] = b_hh[DIM + c];     bias[ct][5] = b_hh[2 * DIM + c];
  }

  // ---- stage B once: 6*25*32 = 4800 uint4 units via global_load_lds ----
  {
    uint4* BbF = &Bb[0][0][0];
    for (int i2 = 0; i2 < 19; ++i2) {
      int u = tid + i2 * 256;
      if (u < 4800) {
        int mat = u / 800;
        int rem = u - mat * 800;
        int ch = rem >> 5;
        int c = rem & 31;
        int gc = cc0 + c; if (gc > 199) gc = 199;
        const ushort* wsrc = (mat & 1) ? whB : wcB;
        GLL16(wsrc + (size_t)((mat >> 1) * DIM + gc) * DIM + ch * 8, BbF + u);
      }
    }
  }
  __syncthreads();   // the ONLY block-wide barrier

  for (int j = 0; j < PPC; ++j) {
    int p = chunk * PPC + j;
    if (p >= NPAN) break;
    int prow0 = p * 128;
    int r0 = prow0 + wv * 32 + lr;
    int r1 = r0 + 16;
    int rc0 = r0 < NN ? r0 : NN - 1;
    int rc1 = r1 < NN ? r1 : NN - 1;
    const ushort* a0 = aggHi + (size_t)rc0 * DIM;
    const ushort* a1 = aggHi + (size_t)rc1 * DIM;
    const ushort* h0 = hHi + (size_t)rc0 * DIM;
    const ushort* h1 = hHi + (size_t)rc1 * DIM;

    // hoisted per-panel output row bases (32-bit), reused by hv-prefetch + stores
    uint rbase[2][4];
    bool rok[2][4];
#pragma unroll
    for (int rf = 0; rf < 2; ++rf)
#pragma unroll
      for (int qq = 0; qq < 4; ++qq) {
        int r_ = prow0 + wv * 32 + rf * 16 + kc * 4 + qq;
        rok[rf][qq] = r_ < NN;
        rbase[rf][qq] = (uint)(r_ < NN ? r_ : NN - 1) * DIM;
      }

    f32x4 acc[3][2][2][2] = {};   // [gate][mat 0=agg,1=h][rf][ct]
    short8 aq[4][2][2];           // [ring4][mat][rf], 3-deep prefetch
    ushort hvh[2][2][4], hvl[2][2][4];   // prefetched h-state for epilogue

#define LDA(d, t)                                                              \
  {                                                                            \
    const bool v_ = ((t) < 6) || (kc == 0);                                    \
    const int of_ = v_ ? ((t) * 32 + kc * 8) : 0;                              \
    const short8 z_ = {0, 0, 0, 0, 0, 0, 0, 0};                                \
    aq[d][0][0] = v_ ? *reinterpret_cast<const short8*>(a0 + of_) : z_;        \
    aq[d][0][1] = v_ ? *reinterpret_cast<const short8*>(a1 + of_) : z_;        \
    aq[d][1][0] = v_ ? *reinterpret_cast<const short8*>(h0 + of_) : z_;        \
    aq[d][1][1] = v_ ? *reinterpret_cast<const short8*>(h1 + of_) : z_;        \
  }

    LDA(0, 0)
    LDA(1, 1)
    LDA(2, 2)
#pragma unroll
    for (int t = 0; t < 7; ++t) {
      const int cur = t & 3;
      if (t < 4) LDA((t + 3) & 3, t + 3)
      if (t == 5) {
        // prefetch epilogue h-state under the last two ktiles' MFMA
#pragma unroll
        for (int ct = 0; ct < 2; ++ct) {
          int cc = ct ? c1c : c0c;
#pragma unroll
          for (int rf = 0; rf < 2; ++rf)
#pragma unroll
            for (int qq = 0; qq < 4; ++qq) {
              uint base = rbase[rf][qq] + cc;
              hvh[ct][rf][qq] = hHi[base];
              hvl[ct][rf][qq] = hLo[base];
            }
        }
      }
      int bch = t * 4 + kc; if (bch > 24) bch = 24;
      __builtin_amdgcn_s_setprio(1);
#pragma unroll
      for (int g = 0; g < 3; ++g) {
#pragma unroll
        for (int ct = 0; ct < 2; ++ct) {
          short8 b1 = *reinterpret_cast<const short8*>(&Bb[g * 2 + 0][bch][ct * 16 + lr]);
          short8 b2 = *reinterpret_cast<const short8*>(&Bb[g * 2 + 1][bch][ct * 16 + lr]);
#pragma unroll
          for (int rf = 0; rf < 2; ++rf) {
            acc[g][0][rf][ct] = MFMA16(aq[cur][0][rf], b1, acc[g][0][rf][ct]);
            acc[g][1][rf][ct] = MFMA16(aq[cur][1][rf], b2, acc[g][1][rf][ct]);
          }
        }
      }
      __builtin_amdgcn_s_setprio(0);
    }
#undef LDA

    // ---- epilogue: GRU gates for this wave's 32x32 tile ----
#pragma unroll
    for (int ct = 0; ct < 2; ++ct) {
      if (!(ct ? c1ok : c0ok)) continue;
      int cc = ct ? c1 : c0;
#pragma unroll
      for (int rf = 0; rf < 2; ++rf) {
#pragma unroll
        for (int qq = 0; qq < 4; ++qq) {
          if (!rok[rf][qq]) continue;
          uint base = rbase[rf][qq] + cc;
          float gir = acc[0][0][rf][ct][qq] + bias[ct][0];
          float giz = acc[1][0][rf][ct][qq] + bias[ct][1];
          float gin = acc[2][0][rf][ct][qq] + bias[ct][2];
          float ghr = acc[0][1][rf][ct][qq] + bias[ct][3];
          float ghz = acc[1][1][rf][ct][qq] + bias[ct][4];
          float ghn = acc[2][1][rf][ct][qq] + bias[ct][5];
          float rr = fsig(gir + ghr);
          float zz = fsig(giz + ghz);
          float nn = ftanh(gin + rr * ghn);
          float hv = bfu(hvh[ct][rf][qq]) + bfu(hvl[ct][rf][qq]);   // exact h state
          uint w = packf_tr(fmaf(zz, hv - nn, nn));
          hnHi[base] = (ushort)(w >> 16);
          hnLo[base] = (ushort)(w & 0xffffu);
        }
      }
    }
  }
}

// ---------------- relu + segment_max pooling ----------------
__global__ __launch_bounds__(256) void k_pool(const ushort* __restrict__ hHi,
                                              const ushort* __restrict__ hLo,
                                              const int* __restrict__ batch,
                                              float* __restrict__ pooled) {
  int i = blockIdx.x;
  int j = threadIdx.x;
  if (j < DIM) {
    int g = batch[i];
    size_t base = (size_t)i * DIM + j;
    float v = bfu(hHi[base]) + bfu(hLo[base]);
    v = v > 0.f ? v : 0.f;
    atomicMax((int*)&pooled[(size_t)g * DIM + j], __float_as_int(v));
  }
}

__global__ __launch_bounds__(256) void k_classify(const float* __restrict__ pooled,
                                                  const float* __restrict__ w,
                                                  const float* __restrict__ b,
                                                  float* __restrict__ out) {
  __shared__ float r0[256], r1[256];
  int g = blockIdx.x;
  int j = threadIdx.x;
  float p = (j < DIM) ? pooled[(size_t)g * DIM + j] : 0.f;
  r0[j] = (j < DIM) ? p * w[j] : 0.f;
  r1[j] = (j < DIM) ? p * w[DIM + j] : 0.f;
  __syncthreads();
  for (int d = 128; d > 0; d >>= 1) {
    if (j < d) { r0[j] += r0[j + d]; r1[j] += r1[j + d]; }
    __syncthreads();
  }
  if (j == 0) {
    out[g * 2 + 0] = 1.f / (1.f + expf(-(r0[0] + b[0])));
    out[g * 2 + 1] = 1.f / (1.f + expf(-(r1[0] + b[1])));
  }
}

// ---------------- host ----------------
extern "C" void kernel_launch(void* const* d_in, const int* in_sizes, int n_in,
                              void* d_out, int out_size, void* d_ws, size_t ws_size,
                              hipStream_t stream) {
  const float* x = (const float*)d_in[0];
  const int* edge_index = (const int*)d_in[1];
  const int* batch = (const int*)d_in[2];
  const float* ggnn_w = (const float*)d_in[3];
  const float* w_ih = (const float*)d_in[4];
  const float* w_hh = (const float*)d_in[5];
  const float* b_ih = (const float*)d_in[6];
  const float* b_hh = (const float*)d_in[7];
  const float* cls_w = (const float*)d_in[8];
  const float* cls_b = (const float*)d_in[9];
  float* out = (float*)d_out;

  const int* src = edge_index;       // edge_index[0]
  const int* dst = edge_index + NE;  // edge_index[1]

  char* wsb = (char*)d_ws;
  size_t off = 0;
  auto alloc = [&](size_t bytes) -> void* {
    void* p = wsb + off;
    off += (bytes + 255) & ~(size_t)255;
    return p;
  };
  ushort* hHiA = (ushort*)alloc((size_t)NN * DIM * 2);   // 20 MB
  ushort* hLoA = (ushort*)alloc((size_t)NN * DIM * 2);   // 20 MB
  ushort* hHiB = (ushort*)alloc((size_t)NN * DIM * 2);   // 20 MB
  ushort* hLoB = (ushort*)alloc((size_t)NN * DIM * 2);   // 20 MB
  ushort* aggHi = (ushort*)alloc((size_t)NN * DIM * 2);  // 20 MB
  ushort* wcB = (ushort*)alloc((size_t)NSTEPS * 3 * DIM * DIM * 2);  // 1.44 MB
  ushort* whB = (ushort*)alloc((size_t)3 * DIM * DIM * 2);           // 240 KB
  float* pooled = (float*)alloc((size_t)NG * DIM * 4);
  int* indeg = (int*)alloc((size_t)NN * 4);
  int* offs = (int*)alloc((size_t)(NN + 1) * 4);
  int* incl = (int*)alloc((size_t)NN * 4);
  int* bsum = (int*)alloc((size_t)256 * 4);
  int* cursor = (int*)alloc((size_t)NN * 4);
  int* slist = (int*)alloc((size_t)NE * 4);
  if (off > ws_size) return;  // fail loud (absmax) instead of faulting

  const int NB = (NN + 255) / 256;   // 196

  // h0 split
  k_pack_split<<<2048, 256, 0, stream>>>(x, hHiA, hLoA, NN * DIM / 8);

  // CSR build (dst -> src list): hist -> 3-kernel hierarchical scan -> scatter
  k_zero_i32<<<196, 256, 0, stream>>>(indeg, NN);
  k_hist<<<(NE + 255) / 256, 256, 0, stream>>>(dst, indeg, NE);
  k_scan_blk<<<NB, 256, 0, stream>>>(indeg, incl, bsum, NN);
  k_scan_top<<<1, 256, 0, stream>>>(bsum, NB);
  k_scan_fin<<<NB, 256, 0, stream>>>(indeg, incl, bsum, offs, cursor, NN);
  k_scatter<<<(NE + 255) / 256, 256, 0, stream>>>(dst, src, cursor, slist, NE);

  // weights: wcB[s] = bf16((ggnn_w[s] @ w_ih^T)^T) in ONE batched launch; whB = bf16(w_hh)
  {
    dim3 g((3 * DIM + GBN - 1) / GBN, (DIM + GBM - 1) / GBM, NSTEPS);
    k_gemm_wc<<<g, 256, 0, stream>>>(ggnn_w, w_ih, wcB);
    k_pack_bf<<<512, 256, 0, stream>>>(w_hh, whB, 3 * DIM * DIM);
  }

  ushort* hHic = hHiA;
  ushort* hLoc = hLoA;
  ushort* hHin = hHiB;
  ushort* hLon = hLoB;
  for (int s = 0; s < NSTEPS; ++s) {
    k_aggregate_hi<<<(NN / 2 + 3) / 4, 256, 0, stream>>>(hHic, offs, slist, aggHi);
    k_fused_mfma<<<GRIDF, 256, 0, stream>>>(aggHi, hHic, hLoc,
                                            wcB + (size_t)s * 3 * DIM * DIM,
                                            whB, b_ih, b_hh, hHin, hLon);
    ushort* t;
    t = hHic; hHic = hHin; hHin = t;
    t = hLoc; hLoc = hLon; hLon = t;
  }

  k_zero_f32<<<200, 256, 0, stream>>>(pooled, NG * DIM);
  k_pool<<<NN, 256, 0, stream>>>(hHic, hLoc, batch, pooled);
  k_classify<<<NG, 256, 0, stream>>>(pooled, cls_w, cls_b, out);
}